// Round 9
// baseline (968.108 us; speedup 1.0000x reference)
//
#include <hip/hip_runtime.h>
#include <math.h>

#define BB 512
#define LL 1024
#define EMB 4
#define CC 64
#define NTF 200
#define TT 247      // seq len after conv1
#define LP 254      // after pool
#define D2 128

typedef __attribute__((ext_vector_type(8))) short short8;
typedef __attribute__((ext_vector_type(4))) float f32x4;
typedef __attribute__((ext_vector_type(4))) unsigned int uint4v;

__device__ __forceinline__ float sigf(float x) { return 1.0f / (1.0f + __expf(-x)); }
__device__ __forceinline__ float tanhff(float x) {
  return 1.0f - 2.0f / (__expf(2.0f * x) + 1.0f);
}

// f32 -> bf16 round-to-nearest-even (finite inputs)
__device__ __forceinline__ unsigned short bfr(float f) {
  unsigned u = __builtin_bit_cast(unsigned, f);
  u += 0x7fffu + ((u >> 16) & 1u);
  return (unsigned short)(u >> 16);
}

// ---- split signal/wait wave sync on LDS flags (replaces s_barrier) ----
// signal: drain own LDS ops, then post monotonic event value.
// wait: poll all 4 wave flags until >= target. Exact rendezvous.
__device__ __forceinline__ void wv_signal(volatile unsigned* flags, int w, int lane, unsigned v) {
  __asm__ __volatile__("" ::: "memory");
  __builtin_amdgcn_s_waitcnt(0xC07F);       // lgkmcnt(0): h-writes visible first
  if (lane == 0) flags[w] = v;
}
__device__ __forceinline__ void wv_wait(volatile unsigned* flags, unsigned v) {
  while (flags[0] < v || flags[1] < v || flags[2] < v || flags[3] < v) {}
  __asm__ __volatile__("" ::: "memory");
}

// ---------------- K0: convert weights to bf16 in ws + lstm bias sums ----------------
__global__ __launch_bounds__(256) void k_cvt(const float* __restrict__ w0,
    const float* __restrict__ w1,
    const float* __restrict__ wihf, const float* __restrict__ whhf,
    const float* __restrict__ wihb, const float* __restrict__ whhb,
    const float* __restrict__ bihf, const float* __restrict__ bhhf,
    const float* __restrict__ bihb, const float* __restrict__ bhhb,
    const float* __restrict__ W1w, const float* __restrict__ Vw,
    unsigned short* __restrict__ wbf0, unsigned short* __restrict__ wbf1,
    unsigned short* __restrict__ wihbf, unsigned short* __restrict__ whhbf,
    float* __restrict__ lbias,
    unsigned short* __restrict__ W1bf, unsigned short* __restrict__ Vbf)
{
  int i = blockIdx.x * 256 + threadIdx.x;   // grid 128*256 = 32768
  if (i < 2048) wbf0[i] = bfr(w0[i]);
  if (i < 32768) wbf1[i] = bfr(w1[i]);
  if (i < 16384) {
    wihbf[i] = bfr(wihf[i]);
    wihbf[16384 + i] = bfr(wihb[i]);
    whhbf[i] = bfr(whhf[i]);
    whhbf[16384 + i] = bfr(whhb[i]);
    W1bf[i] = bfr(W1w[i]);
  }
  if (i < 26624) {                           // Vbf padded to 208 rows
    int row = i >> 7;
    Vbf[i] = (row < NTF) ? bfr(Vw[i]) : (unsigned short)0;
  }
  if (i < 256) {
    lbias[i] = bihf[i] + bhhf[i];
    lbias[256 + i] = bihb[i] + bhhb[i];
  }
}

// ---------------- K1: conv0 + BN + ReLU + maxpool(4), MFMA ----------------
__global__ __launch_bounds__(256) void k_conv0m(const float* __restrict__ x,
    const unsigned short* __restrict__ wbf0,
    const float* __restrict__ b0, const float* __restrict__ g0,
    const float* __restrict__ be0, const float* __restrict__ m0,
    const float* __restrict__ v0, float* __restrict__ p)
{
  int b = blockIdx.x, l0 = blockIdx.y * 64;
  __shared__ float xs[71 * 4];
  __shared__ float sc[64], sb[64];
  int tid = threadIdx.x;
  for (int j = tid; j < 71; j += 256) {
    int l = l0 + j;
    float4 xv = (l < LL) ? *(const float4*)(x + ((size_t)b * LL + l) * EMB)
                         : make_float4(0.f, 0.f, 0.f, 0.f);
    *(float4*)(xs + j * 4) = xv;
  }
  if (tid < 64) {
    float s = g0[tid] * rsqrtf(v0[tid] + 1e-5f);
    sc[tid] = s;
    sb[tid] = (b0[tid] - m0[tid]) * s + be0[tid];
  }
  __syncthreads();
  int w = tid >> 6, lane = tid & 63, nl = lane & 15, quad = lane >> 4;
  const float* ap = xs + (w * 16 + nl) * 4 + quad;
  short8 af;
  #pragma unroll
  for (int j = 0; j < 8; ++j) af[j] = (short)bfr(ap[j * 4]);
  f32x4 acc[4];
  #pragma unroll
  for (int nt = 0; nt < 4; ++nt) {
    short8 bf = __builtin_bit_cast(short8,
        *(const uint4v*)(wbf0 + ((nt * 16 + nl) * 32 + quad * 8)));
    acc[nt] = (f32x4){0.f, 0.f, 0.f, 0.f};
    acc[nt] = __builtin_amdgcn_mfma_f32_16x16x32_bf16(af, bf, acc[nt], 0, 0, 0);
  }
  int t = (l0 >> 2) + w * 4 + quad;
  if (t < LP) {
    #pragma unroll
    for (int nt = 0; nt < 4; ++nt) {
      int c = nt * 16 + nl;
      float scc = sc[c], sbc = sb[c];
      float mx = -1e30f;
      #pragma unroll
      for (int r = 0; r < 4; ++r) mx = fmaxf(mx, acc[nt][r] * scc + sbc);
      p[((size_t)b * LP + t) * CC + c] = fmaxf(mx, 0.0f);
    }
  }
}

// ---------------- K2: conv1 + BN + ReLU -> x2bf[b][t][c] (bf16), MFMA ----------------
__global__ __launch_bounds__(256) void k_conv1m(const float* __restrict__ p,
    const unsigned short* __restrict__ wbf1,
    const float* __restrict__ b1, const float* __restrict__ g1,
    const float* __restrict__ be1, const float* __restrict__ m1,
    const float* __restrict__ v1, unsigned short* __restrict__ x2bf)
{
  int b = blockIdx.x, t0 = blockIdx.y * 64;
  __shared__ float As[71 * 68];
  __shared__ float sc[64], sb[64];
  int tid = threadIdx.x;
  for (int j = tid; j < 71 * 64; j += 256) {
    int col = j >> 6, ci = j & 63;
    int t = t0 + col;
    As[col * 68 + ci] = (t < LP) ? p[((size_t)b * LP + t) * CC + ci] : 0.0f;
  }
  if (tid < 64) {
    float s = g1[tid] * rsqrtf(v1[tid] + 1e-5f);
    sc[tid] = s;
    sb[tid] = (b1[tid] - m1[tid]) * s + be1[tid];
  }
  __syncthreads();
  int w = tid >> 6, lane = tid & 63, nl = lane & 15, quad = lane >> 4;
  const float* ap = As + (w * 16 + nl) * 68;
  f32x4 acc[4];
  #pragma unroll
  for (int nt = 0; nt < 4; ++nt) acc[nt] = (f32x4){0.f, 0.f, 0.f, 0.f};
  for (int ks = 0; ks < 16; ++ks) {
    int ci = ks * 4 + quad;
    short8 af;
    #pragma unroll
    for (int j = 0; j < 8; ++j) af[j] = (short)bfr(ap[j * 68 + ci]);
    #pragma unroll
    for (int nt = 0; nt < 4; ++nt) {
      short8 bf = __builtin_bit_cast(short8,
          *(const uint4v*)(wbf1 + ((size_t)(nt * 16 + nl) * 512 + ci * 8)));
      acc[nt] = __builtin_amdgcn_mfma_f32_16x16x32_bf16(af, bf, acc[nt], 0, 0, 0);
    }
  }
  #pragma unroll
  for (int nt = 0; nt < 4; ++nt) {
    int c = nt * 16 + nl;
    float scc = sc[c], sbc = sb[c];
    #pragma unroll
    for (int r = 0; r < 4; ++r) {
      int t = t0 + w * 16 + quad * 4 + r;
      if (t < TT)
        x2bf[((size_t)b * TT + t) * CC + c] = bfr(fmaxf(acc[nt][r] * scc + sbc, 0.0f));
    }
  }
}

// ---------------- K3: bi-LSTM via MFMA, chunked I/O, flag-sync (no s_barrier) ----------------
// Events per chunk: 8 step-signals + 1 boundary-signal. Step (c,sl) waits for
// value 9c+sl (all waves done step s-1 / boundary staging); boundary waits 9c+8.
// x-part MFMAs are hoisted ABOVE the wait (xls is chunk-stable) to shorten the
// post-wait serial chain to: ds_read h -> 8 MFMA -> nonlin -> write -> signal.
__global__ __launch_bounds__(256) void k_lstm_m(const unsigned short* __restrict__ x2bf,
    const unsigned short* __restrict__ wihbf, const unsigned short* __restrict__ whhbf,
    const float* __restrict__ lbias,
    unsigned short* __restrict__ values, float* __restrict__ hT)
{
  int b0 = blockIdx.x * 16;
  int dir = blockIdx.y;
  int tid = threadIdx.x;
  int w = tid >> 6, lane = tid & 63, l15 = lane & 15, quad = lane >> 4;
  int h0 = w * 16;
  const unsigned short* wih = wihbf + dir * 16384;
  const unsigned short* whh = whhbf + dir * 16384;

  short8 bx[4][2], bh[4][2];
  float bias_v[4];
  #pragma unroll
  for (int g = 0; g < 4; ++g) {
    int row = g * 64 + h0 + l15;
    #pragma unroll
    for (int k = 0; k < 2; ++k) {
      bx[g][k] = __builtin_bit_cast(short8, *(const uint4v*)(wih + row * 64 + k * 32 + quad * 8));
      bh[g][k] = __builtin_bit_cast(short8, *(const uint4v*)(whh + row * 64 + k * 32 + quad * 8));
    }
    bias_v[g] = lbias[dir * 256 + g * 64 + h0 + l15];
  }

  __shared__ __align__(16) unsigned short xls[2][8][16 * 72];
  __shared__ __align__(16) unsigned short hist[8][16 * 72];
  __shared__ unsigned sflags[4];
  volatile unsigned* flags = (volatile unsigned*)sflags;
  if (tid < 4) sflags[tid] = 0;
  for (int j = tid; j < 16 * 72; j += 256) hist[7][j] = 0;  // h_{-1} = 0

  int bl = tid >> 4, d4 = tid & 15;
  const unsigned short* xrow = x2bf + ((size_t)(b0 + bl) * TT) * 64 + d4 * 4;

  uint2 xr[8];
  #pragma unroll
  for (int k = 0; k < 8; ++k) {               // chunk 0
    int t = dir ? (TT - 1 - k) : k;
    xr[k] = *(const uint2*)(xrow + (size_t)t * 64);
  }
  #pragma unroll
  for (int k = 0; k < 8; ++k)
    *(uint2*)(&xls[0][k][bl * 72 + d4 * 4]) = xr[k];
  #pragma unroll
  for (int k = 0; k < 8; ++k) {               // chunk 1
    int s = 8 + k;
    int t = dir ? (TT - 1 - s) : s;
    xr[k] = *(const uint2*)(xrow + (size_t)t * 64);
  }
  __syncthreads();

  float cst[4] = {0.f, 0.f, 0.f, 0.f};
  for (int c = 0; c < 31; ++c) {
    int buf = c & 1;
    unsigned evb = 9u * (unsigned)c;
    #pragma unroll
    for (int sl = 0; sl < 8; ++sl) {
      int hp = (sl + 7) & 7;
      if (sl == 0) wv_wait(flags, evb);       // covers prev boundary staging too
      short8 ax0 = __builtin_bit_cast(short8, *(const uint4v*)(&xls[buf][sl][l15 * 72 + quad * 8]));
      short8 ax1 = __builtin_bit_cast(short8, *(const uint4v*)(&xls[buf][sl][l15 * 72 + 32 + quad * 8]));
      f32x4 aX[4];
      #pragma unroll
      for (int g = 0; g < 4; ++g) {
        aX[g] = (f32x4){bias_v[g], bias_v[g], bias_v[g], bias_v[g]};
        aX[g] = __builtin_amdgcn_mfma_f32_16x16x32_bf16(ax0, bx[g][0], aX[g], 0, 0, 0);
        aX[g] = __builtin_amdgcn_mfma_f32_16x16x32_bf16(ax1, bx[g][1], aX[g], 0, 0, 0);
      }
      if (sl != 0) wv_wait(flags, evb + sl);  // all waves done step s-1
      short8 ah0 = __builtin_bit_cast(short8, *(const uint4v*)(&hist[hp][l15 * 72 + quad * 8]));
      short8 ah1 = __builtin_bit_cast(short8, *(const uint4v*)(&hist[hp][l15 * 72 + 32 + quad * 8]));
      f32x4 aH[4];
      #pragma unroll
      for (int g = 0; g < 4; ++g) {
        aH[g] = (f32x4){0.f, 0.f, 0.f, 0.f};
        aH[g] = __builtin_amdgcn_mfma_f32_16x16x32_bf16(ah0, bh[g][0], aH[g], 0, 0, 0);
        aH[g] = __builtin_amdgcn_mfma_f32_16x16x32_bf16(ah1, bh[g][1], aH[g], 0, 0, 0);
      }
      #pragma unroll
      for (int r = 0; r < 4; ++r) {
        float ig = sigf(aX[0][r] + aH[0][r]);
        float fg = sigf(aX[1][r] + aH[1][r]);
        float gg = tanhff(aX[2][r] + aH[2][r]);
        float og = sigf(aX[3][r] + aH[3][r]);
        cst[r] = fg * cst[r] + ig * gg;
        float hh = og * tanhff(cst[r]);
        hist[sl][(quad * 4 + r) * 72 + h0 + l15] = bfr(hh);
        if (c == 30 && sl == 6) {             // global step 246 = last real step
          int bglob = b0 + quad * 4 + r;
          hT[((size_t)dir * BB + bglob) * 64 + h0 + l15] = hh;
        }
      }
      wv_signal(flags, w, lane, evb + sl + 1);
    }
    // ---- boundary: all steps of chunk done -> dump hist -> values
    wv_wait(flags, evb + 8);
    uint4v dv[4];
    #pragma unroll
    for (int i = 0; i < 4; ++i) {
      int flat = i * 256 + tid;
      int sl = flat >> 7, wb = (flat >> 3) & 15, c8 = flat & 7;
      dv[i] = *(const uint4v*)(&hist[sl][wb * 72 + c8 * 8]);
    }
    #pragma unroll
    for (int i = 0; i < 4; ++i) {
      int flat = i * 256 + tid;
      int sl = flat >> 7, wb = (flat >> 3) & 15, c8 = flat & 7;
      int s = c * 8 + sl;
      if (s < TT) {
        int t = dir ? (TT - 1 - s) : s;
        *(uint4v*)(values + ((size_t)(b0 + wb) * TT + t) * D2 + dir * 64 + c8 * 8) = dv[i];
      }
    }
    if (c < 30) {
      #pragma unroll
      for (int k = 0; k < 8; ++k)
        *(uint2*)(&xls[1 - buf][k][bl * 72 + d4 * 4]) = xr[k];
      #pragma unroll
      for (int k = 0; k < 8; ++k) {
        int s2 = (c + 2) * 8 + k;
        if (s2 > TT - 1) s2 = TT - 1;
        int t2 = dir ? (TT - 1 - s2) : s2;
        xr[k] = *(const uint2*)(xrow + (size_t)t2 * 64);
      }
    }
    wv_signal(flags, w, lane, evb + 9);       // dump reads + staging drained
  }
}

// ---------------- K3b: q2 = h_n @ W2^T + W2_b ----------------
__global__ __launch_bounds__(128) void k_q2(const float* __restrict__ hT,
    const float* __restrict__ W2, const float* __restrict__ W2b,
    float* __restrict__ q2)
{
  int b = blockIdx.x;
  int tid = threadIdx.x;
  __shared__ float4 hn4[32];
  ((float*)hn4)[tid] = hT[(size_t)b * 128 + tid];
  __syncthreads();
  const float4* w4 = (const float4*)(W2 + (size_t)tid * 128);
  float a = W2b[tid];
  #pragma unroll
  for (int j = 0; j < 32; ++j) {
    float4 w = w4[j]; float4 h = hn4[j];
    a += w.x * h.x + w.y * h.y + w.z * h.z + w.w * h.w;
  }
  q2[(size_t)b * 128 + tid] = a;
}

// ---------------- K4: score via MFMA ----------------
__global__ __launch_bounds__(256) void k_score_m(const unsigned short* __restrict__ vbf,
    const unsigned short* __restrict__ W1bf, const float* __restrict__ W1b,
    const float* __restrict__ q2, const unsigned short* __restrict__ Vbf,
    const float* __restrict__ Vb, float* __restrict__ score)
{
  int b = blockIdx.x, t0 = blockIdx.y * 64;
  int tid = threadIdx.x, w = tid >> 6, lane = tid & 63, l15 = lane & 15, quad = lane >> 4;
  __shared__ unsigned short us[64 * 136];
  const unsigned short* arow = vbf + ((size_t)b * TT + t0 + w * 16 + l15) * 128;
  short8 ax[4];
  #pragma unroll
  for (int ks = 0; ks < 4; ++ks)
    ax[ks] = __builtin_bit_cast(short8, *(const uint4v*)(arow + ks * 32 + quad * 8));
  #pragma unroll
  for (int nt = 0; nt < 8; ++nt) {
    int n = nt * 16 + l15;
    float base = W1b[n] + q2[(size_t)b * 128 + n];
    f32x4 acc = (f32x4){base, base, base, base};
    #pragma unroll
    for (int ks = 0; ks < 4; ++ks) {
      short8 bf = __builtin_bit_cast(short8,
          *(const uint4v*)(W1bf + (size_t)n * 128 + ks * 32 + quad * 8));
      acc = __builtin_amdgcn_mfma_f32_16x16x32_bf16(ax[ks], bf, acc, 0, 0, 0);
    }
    #pragma unroll
    for (int r = 0; r < 4; ++r)
      us[(w * 16 + quad * 4 + r) * 136 + nt * 16 + l15] = bfr(tanhff(acc[r]));
  }
  __syncthreads();
  short8 au[4];
  #pragma unroll
  for (int ks = 0; ks < 4; ++ks)
    au[ks] = __builtin_bit_cast(short8, *(const uint4v*)(&us[(w * 16 + l15) * 136 + ks * 32 + quad * 8]));
  for (int nt2 = 0; nt2 < 13; ++nt2) {
    int n = nt2 * 16 + l15;
    float b2 = (n < NTF) ? Vb[n] : 0.0f;
    f32x4 a2 = (f32x4){b2, b2, b2, b2};
    #pragma unroll
    for (int ks = 0; ks < 4; ++ks) {
      short8 bf = __builtin_bit_cast(short8,
          *(const uint4v*)(Vbf + (size_t)n * 128 + ks * 32 + quad * 8));
      a2 = __builtin_amdgcn_mfma_f32_16x16x32_bf16(au[ks], bf, a2, 0, 0, 0);
    }
    #pragma unroll
    for (int r = 0; r < 4; ++r) {
      int t = t0 + w * 16 + quad * 4 + r;
      if (t < TT && n < NTF) score[((size_t)b * TT + t) * NTF + n] = a2[r];
    }
  }
}

// ---------------- K5: softmax over t, 4x unrolled (stores unnorm exp + 1/sum) ----------------
__global__ __launch_bounds__(256) void k_softmax(float* __restrict__ score,
    float* __restrict__ sinv)
{
  int b = blockIdx.x;
  int n = threadIdx.x;
  if (n >= NTF) return;
  size_t base = (size_t)b * TT * NTF + n;
  float m0 = -1e30f, m1 = -1e30f, m2 = -1e30f, m3 = -1e30f;
  int t = 0;
  for (; t + 4 <= TT; t += 4) {
    float a = score[base + (size_t)t * NTF];
    float bb = score[base + (size_t)(t + 1) * NTF];
    float cc = score[base + (size_t)(t + 2) * NTF];
    float dd = score[base + (size_t)(t + 3) * NTF];
    m0 = fmaxf(m0, a); m1 = fmaxf(m1, bb); m2 = fmaxf(m2, cc); m3 = fmaxf(m3, dd);
  }
  for (; t < TT; ++t) m0 = fmaxf(m0, score[base + (size_t)t * NTF]);
  float m = fmaxf(fmaxf(m0, m1), fmaxf(m2, m3));
  float s0 = 0.f, s1 = 0.f, s2 = 0.f, s3 = 0.f;
  for (t = 0; t + 4 <= TT; t += 4) {
    float a = __expf(score[base + (size_t)t * NTF] - m);
    float bb = __expf(score[base + (size_t)(t + 1) * NTF] - m);
    float cc = __expf(score[base + (size_t)(t + 2) * NTF] - m);
    float dd = __expf(score[base + (size_t)(t + 3) * NTF] - m);
    score[base + (size_t)t * NTF] = a;
    score[base + (size_t)(t + 1) * NTF] = bb;
    score[base + (size_t)(t + 2) * NTF] = cc;
    score[base + (size_t)(t + 3) * NTF] = dd;
    s0 += a; s1 += bb; s2 += cc; s3 += dd;
  }
  for (; t < TT; ++t) {
    float e = __expf(score[base + (size_t)t * NTF] - m);
    score[base + (size_t)t * NTF] = e;
    s0 += e;
  }
  sinv[(size_t)b * NTF + n] = 1.0f / (s0 + s1 + s2 + s3);
}

// ---------------- K6: context via MFMA ----------------
__global__ __launch_bounds__(256) void k_ctx_m(const unsigned short* __restrict__ vbf,
    const float* __restrict__ score, const float* __restrict__ sinv,
    float* __restrict__ ctx)
{
  int b = blockIdx.x;
  int tid = threadIdx.x, w = tid >> 6, lane = tid & 63, l15 = lane & 15, quad = lane >> 4;
  __shared__ unsigned short ascore[208 * 40];
  __shared__ unsigned short bval[128 * 40];
  __shared__ float sls[208];
  for (int j = tid; j < 208; j += 256) sls[j] = (j < NTF) ? sinv[(size_t)b * NTF + j] : 0.0f;

  f32x4 acc[4][8];
  #pragma unroll
  for (int i = 0; i < 4; ++i)
    #pragma unroll
    for (int nt = 0; nt < 8; ++nt) acc[i][nt] = (f32x4){0.f, 0.f, 0.f, 0.f};

  for (int ch = 0; ch < 8; ++ch) {
    int tc = ch * 32;
    __syncthreads();
    for (int j = tid; j < 32 * 256; j += 256) {
      int tl = j >> 8, n = j & 255;
      if (n < 208) {
        int t = tc + tl;
        float v = (n < NTF && t < TT) ? score[((size_t)b * TT + t) * NTF + n] : 0.0f;
        ascore[n * 40 + tl] = bfr(v);
      }
    }
    for (int j = tid; j < 32 * 64; j += 256) {
      int tl = j >> 6, d2 = j & 63;
      int t = tc + tl;
      unsigned v = (t < TT) ? *(const unsigned*)(vbf + ((size_t)b * TT + t) * D2 + d2 * 2) : 0u;
      bval[(d2 * 2) * 40 + tl] = (unsigned short)(v & 0xffffu);
      bval[(d2 * 2 + 1) * 40 + tl] = (unsigned short)(v >> 16);
    }
    __syncthreads();
    short8 bv[8];
    #pragma unroll
    for (int nt = 0; nt < 8; ++nt)
      bv[nt] = __builtin_bit_cast(short8, *(const uint4v*)(&bval[(nt * 16 + l15) * 40 + quad * 8]));
    #pragma unroll
    for (int i = 0; i < 4; ++i) {
      int mt = w + 4 * i;
      if (mt < 13) {
        short8 au = __builtin_bit_cast(short8, *(const uint4v*)(&ascore[(mt * 16 + l15) * 40 + quad * 8]));
        #pragma unroll
        for (int nt = 0; nt < 8; ++nt)
          acc[i][nt] = __builtin_amdgcn_mfma_f32_16x16x32_bf16(au, bv[nt], acc[i][nt], 0, 0, 0);
      }
    }
  }
  #pragma unroll
  for (int i = 0; i < 4; ++i) {
    int mt = w + 4 * i;
    if (mt < 13) {
      #pragma unroll
      for (int r = 0; r < 4; ++r) {
        int n = mt * 16 + quad * 4 + r;
        if (n < NTF) {
          float rs = sls[n];
          #pragma unroll
          for (int nt = 0; nt < 8; ++nt) {
            int d = nt * 16 + l15;
            ctx[((size_t)b * NTF + n) * D2 + d] = acc[i][nt][r] * rs;
          }
        }
      }
    }
  }
}

// ---------------- K7: per-TF heads ----------------
__global__ __launch_bounds__(256) void k_heads(const float* __restrict__ ctx,
    const float* __restrict__ fc1w, const float* __restrict__ fc1b,
    const float* __restrict__ fc2w, const float* __restrict__ fc2b,
    float* __restrict__ out)
{
  int n = blockIdx.x;
  int bq = blockIdx.y;
  int tid = threadIdx.x;
  int o = tid & 63, w = tid >> 6;
  __shared__ float ctxs[4 * 128];
  float4 fr[32];
  const float4* fp = (const float4*)(fc1w + ((size_t)n * 64 + o) * 128);
  #pragma unroll
  for (int j = 0; j < 32; ++j) fr[j] = fp[j];
  float f1bv = fc1b[n * 64 + o];
  float f2 = fc2w[n * 64 + o];
  float f2b = fc2b[n];
  for (int i = 0; i < 16; ++i) {
    int bbase = bq * 64 + i * 4;
    __syncthreads();
    for (int j = tid; j < 512; j += 256) {
      int ww = j >> 7, k = j & 127;
      ctxs[j] = ctx[((size_t)(bbase + ww) * NTF + n) * D2 + k];
    }
    __syncthreads();
    float a = f1bv;
    const float4* c4 = (const float4*)(ctxs + w * 128);
    #pragma unroll
    for (int j = 0; j < 32; ++j) {
      float4 cv = c4[j];
      float4 fv = fr[j];
      a += cv.x * fv.x + cv.y * fv.y + cv.z * fv.z + cv.w * fv.w;
    }
    float part = fmaxf(a, 0.0f) * f2;
    #pragma unroll
    for (int off = 32; off > 0; off >>= 1)
      part += __shfl_down(part, off, 64);
    if (o == 0) out[(size_t)(bbase + w) * NTF + n] = part + f2b;
  }
}

extern "C" void kernel_launch(void* const* d_in, const int* in_sizes, int n_in,
                              void* d_out, int out_size, void* d_ws, size_t ws_size,
                              hipStream_t stream)
{
  const float* x    = (const float*)d_in[0];
  const float* c0w  = (const float*)d_in[1];
  const float* c0b  = (const float*)d_in[2];
  const float* g0   = (const float*)d_in[3];
  const float* be0  = (const float*)d_in[4];
  const float* m0   = (const float*)d_in[5];
  const float* v0   = (const float*)d_in[6];
  const float* c1w  = (const float*)d_in[7];
  const float* c1b  = (const float*)d_in[8];
  const float* g1   = (const float*)d_in[9];
  const float* be1  = (const float*)d_in[10];
  const float* m1   = (const float*)d_in[11];
  const float* v1   = (const float*)d_in[12];
  const float* wihf = (const float*)d_in[13];
  const float* whhf = (const float*)d_in[14];
  const float* bihf = (const float*)d_in[15];
  const float* bhhf = (const float*)d_in[16];
  const float* wihb = (const float*)d_in[17];
  const float* whhb = (const float*)d_in[18];
  const float* bihb = (const float*)d_in[19];
  const float* bhhb = (const float*)d_in[20];
  const float* W1w  = (const float*)d_in[21];
  const float* W1b  = (const float*)d_in[22];
  const float* W2w  = (const float*)d_in[23];
  const float* W2b  = (const float*)d_in[24];
  const float* Vw   = (const float*)d_in[25];
  const float* Vb   = (const float*)d_in[26];
  const float* f1w  = (const float*)d_in[27];
  const float* f1b  = (const float*)d_in[28];
  const float* f2w  = (const float*)d_in[29];
  const float* f2b  = (const float*)d_in[30];

  float* ws = (float*)d_ws;
  // layout (f32 offsets); p/x2bf overlap score (dead before k_score_m writes)
  float* score  = ws;                         // 25,292,800 f32
  float* p      = ws;                         // 8,323,072
  unsigned short* x2bf = (unsigned short*)(ws + 8323072);  // 8,093,696 bf16
  unsigned short* vbf  = (unsigned short*)(ws + 25292800); // 16,187,392 bf16 (+slack)
  float* hT     = ws + 33387520;              // 65,536
  float* q2     = ws + 33453056;              // 65,536
  float* sinv   = ws + 33518592;              // 102,400
  float* ctx    = ws + 33620992;              // 13,107,200 (ends 46,728,192)
  unsigned short* wbf0  = (unsigned short*)(ws + 46728192);  // 2048
  unsigned short* wbf1  = (unsigned short*)(ws + 46729216);  // 32768
  unsigned short* wihbf = (unsigned short*)(ws + 46745600);  // 32768
  unsigned short* whhbf = (unsigned short*)(ws + 46761984);  // 32768
  float* lbias          = ws + 46778368;                     // 512
  unsigned short* W1bf  = (unsigned short*)(ws + 46778880);  // 16384
  unsigned short* Vbf   = (unsigned short*)(ws + 46787072);  // 26624
  float* out    = (float*)d_out;

  k_cvt<<<dim3(128), 256, 0, stream>>>(c0w, c1w, wihf, whhf, wihb, whhb,
                                       bihf, bhhf, bihb, bhhb, W1w, Vw,
                                       wbf0, wbf1, wihbf, whhbf, lbias, W1bf, Vbf);
  k_conv0m<<<dim3(BB, 16), 256, 0, stream>>>(x, wbf0, c0b, g0, be0, m0, v0, p);
  k_conv1m<<<dim3(BB, 4), 256, 0, stream>>>(p, wbf1, c1b, g1, be1, m1, v1, x2bf);
  k_lstm_m<<<dim3(BB / 16, 2), 256, 0, stream>>>(x2bf, wihbf, whhbf, lbias, vbf, hT);
  k_q2<<<dim3(BB), 128, 0, stream>>>(hT, W2w, W2b, q2);
  k_score_m<<<dim3(BB, 4), 256, 0, stream>>>(vbf, W1bf, W1b, q2, Vbf, Vb, score);
  k_softmax<<<dim3(BB), 256, 0, stream>>>(score, sinv);
  k_ctx_m<<<dim3(BB), 256, 0, stream>>>(vbf, score, sinv, ctx);
  k_heads<<<dim3(NTF, 8), 256, 0, stream>>>(ctx, f1w, f1b, f2w, f2b, out);
}

// Round 10
// 797.270 us; speedup vs baseline: 1.2143x; 1.2143x over previous
//
#include <hip/hip_runtime.h>
#include <math.h>

#define BB 512
#define LL 1024
#define EMB 4
#define CC 64
#define NTF 200
#define TT 247      // seq len after conv1
#define LP 254      // after pool
#define D2 128

typedef __attribute__((ext_vector_type(8))) short short8;
typedef __attribute__((ext_vector_type(4))) float f32x4;
typedef __attribute__((ext_vector_type(4))) unsigned int uint4v;

// Fast nonlinearities: v_rcp_f32 (1 ulp) instead of IEEE division (~10 instr chain).
__device__ __forceinline__ float sigf(float x) {
  return __builtin_amdgcn_rcpf(1.0f + __expf(-x));
}
__device__ __forceinline__ float tanhff(float x) {
  return 1.0f - 2.0f * __builtin_amdgcn_rcpf(__expf(2.0f * x) + 1.0f);
}

// LDS-only barrier: 0xC07F = vmcnt(63)|expcnt(7)|lgkmcnt(0).
__device__ __forceinline__ void lds_barrier() {
  __builtin_amdgcn_s_waitcnt(0xC07F);
  __builtin_amdgcn_s_barrier();
}

// f32 -> bf16 round-to-nearest-even (finite inputs)
__device__ __forceinline__ unsigned short bfr(float f) {
  unsigned u = __builtin_bit_cast(unsigned, f);
  u += 0x7fffu + ((u >> 16) & 1u);
  return (unsigned short)(u >> 16);
}

// ---------------- K0: convert weights to bf16 in ws + lstm bias sums ----------------
__global__ __launch_bounds__(256) void k_cvt(const float* __restrict__ w0,
    const float* __restrict__ w1,
    const float* __restrict__ wihf, const float* __restrict__ whhf,
    const float* __restrict__ wihb, const float* __restrict__ whhb,
    const float* __restrict__ bihf, const float* __restrict__ bhhf,
    const float* __restrict__ bihb, const float* __restrict__ bhhb,
    const float* __restrict__ W1w, const float* __restrict__ Vw,
    unsigned short* __restrict__ wbf0, unsigned short* __restrict__ wbf1,
    unsigned short* __restrict__ wihbf, unsigned short* __restrict__ whhbf,
    float* __restrict__ lbias,
    unsigned short* __restrict__ W1bf, unsigned short* __restrict__ Vbf)
{
  int i = blockIdx.x * 256 + threadIdx.x;   // grid 128*256 = 32768
  if (i < 2048) wbf0[i] = bfr(w0[i]);
  if (i < 32768) wbf1[i] = bfr(w1[i]);
  if (i < 16384) {
    wihbf[i] = bfr(wihf[i]);
    wihbf[16384 + i] = bfr(wihb[i]);
    whhbf[i] = bfr(whhf[i]);
    whhbf[16384 + i] = bfr(whhb[i]);
    W1bf[i] = bfr(W1w[i]);
  }
  if (i < 26624) {                           // Vbf padded to 208 rows
    int row = i >> 7;
    Vbf[i] = (row < NTF) ? bfr(Vw[i]) : (unsigned short)0;
  }
  if (i < 256) {
    lbias[i] = bihf[i] + bhhf[i];
    lbias[256 + i] = bihb[i] + bhhb[i];
  }
}

// ---------------- K1: conv0 + BN + ReLU + maxpool(4), MFMA ----------------
__global__ __launch_bounds__(256) void k_conv0m(const float* __restrict__ x,
    const unsigned short* __restrict__ wbf0,
    const float* __restrict__ b0, const float* __restrict__ g0,
    const float* __restrict__ be0, const float* __restrict__ m0,
    const float* __restrict__ v0, float* __restrict__ p)
{
  int b = blockIdx.x, l0 = blockIdx.y * 64;
  __shared__ float xs[71 * 4];
  __shared__ float sc[64], sb[64];
  int tid = threadIdx.x;
  for (int j = tid; j < 71; j += 256) {
    int l = l0 + j;
    float4 xv = (l < LL) ? *(const float4*)(x + ((size_t)b * LL + l) * EMB)
                         : make_float4(0.f, 0.f, 0.f, 0.f);
    *(float4*)(xs + j * 4) = xv;
  }
  if (tid < 64) {
    float s = g0[tid] * rsqrtf(v0[tid] + 1e-5f);
    sc[tid] = s;
    sb[tid] = (b0[tid] - m0[tid]) * s + be0[tid];
  }
  __syncthreads();
  int w = tid >> 6, lane = tid & 63, nl = lane & 15, quad = lane >> 4;
  const float* ap = xs + (w * 16 + nl) * 4 + quad;
  short8 af;
  #pragma unroll
  for (int j = 0; j < 8; ++j) af[j] = (short)bfr(ap[j * 4]);
  f32x4 acc[4];
  #pragma unroll
  for (int nt = 0; nt < 4; ++nt) {
    short8 bf = __builtin_bit_cast(short8,
        *(const uint4v*)(wbf0 + ((nt * 16 + nl) * 32 + quad * 8)));
    acc[nt] = (f32x4){0.f, 0.f, 0.f, 0.f};
    acc[nt] = __builtin_amdgcn_mfma_f32_16x16x32_bf16(af, bf, acc[nt], 0, 0, 0);
  }
  int t = (l0 >> 2) + w * 4 + quad;
  if (t < LP) {
    #pragma unroll
    for (int nt = 0; nt < 4; ++nt) {
      int c = nt * 16 + nl;
      float scc = sc[c], sbc = sb[c];
      float mx = -1e30f;
      #pragma unroll
      for (int r = 0; r < 4; ++r) mx = fmaxf(mx, acc[nt][r] * scc + sbc);
      p[((size_t)b * LP + t) * CC + c] = fmaxf(mx, 0.0f);
    }
  }
}

// ---------------- K2: conv1 + BN + ReLU -> x2bf[b][t][c] (bf16), MFMA ----------------
__global__ __launch_bounds__(256) void k_conv1m(const float* __restrict__ p,
    const unsigned short* __restrict__ wbf1,
    const float* __restrict__ b1, const float* __restrict__ g1,
    const float* __restrict__ be1, const float* __restrict__ m1,
    const float* __restrict__ v1, unsigned short* __restrict__ x2bf)
{
  int b = blockIdx.x, t0 = blockIdx.y * 64;
  __shared__ float As[71 * 68];
  __shared__ float sc[64], sb[64];
  int tid = threadIdx.x;
  for (int j = tid; j < 71 * 64; j += 256) {
    int col = j >> 6, ci = j & 63;
    int t = t0 + col;
    As[col * 68 + ci] = (t < LP) ? p[((size_t)b * LP + t) * CC + ci] : 0.0f;
  }
  if (tid < 64) {
    float s = g1[tid] * rsqrtf(v1[tid] + 1e-5f);
    sc[tid] = s;
    sb[tid] = (b1[tid] - m1[tid]) * s + be1[tid];
  }
  __syncthreads();
  int w = tid >> 6, lane = tid & 63, nl = lane & 15, quad = lane >> 4;
  const float* ap = As + (w * 16 + nl) * 68;
  f32x4 acc[4];
  #pragma unroll
  for (int nt = 0; nt < 4; ++nt) acc[nt] = (f32x4){0.f, 0.f, 0.f, 0.f};
  for (int ks = 0; ks < 16; ++ks) {
    int ci = ks * 4 + quad;
    short8 af;
    #pragma unroll
    for (int j = 0; j < 8; ++j) af[j] = (short)bfr(ap[j * 68 + ci]);
    #pragma unroll
    for (int nt = 0; nt < 4; ++nt) {
      short8 bf = __builtin_bit_cast(short8,
          *(const uint4v*)(wbf1 + ((size_t)(nt * 16 + nl) * 512 + ci * 8)));
      acc[nt] = __builtin_amdgcn_mfma_f32_16x16x32_bf16(af, bf, acc[nt], 0, 0, 0);
    }
  }
  #pragma unroll
  for (int nt = 0; nt < 4; ++nt) {
    int c = nt * 16 + nl;
    float scc = sc[c], sbc = sb[c];
    #pragma unroll
    for (int r = 0; r < 4; ++r) {
      int t = t0 + w * 16 + quad * 4 + r;
      if (t < TT)
        x2bf[((size_t)b * TT + t) * CC + c] = bfr(fmaxf(acc[nt][r] * scc + sbc, 0.0f));
    }
  }
}

// ---------------- K3: bi-LSTM via MFMA, chunked I/O (R8 structure) ----------------
// Steps issue ZERO vmem. h lives in an 8-slot LDS ring (hist); every 8 steps it
// is dumped with coalesced b128 stores. x for chunk c+1 prefetched into regs
// BEFORE the dump stores (in-order vmcnt never waits on stores).
__global__ __launch_bounds__(256) void k_lstm_m(const unsigned short* __restrict__ x2bf,
    const unsigned short* __restrict__ wihbf, const unsigned short* __restrict__ whhbf,
    const float* __restrict__ lbias,
    unsigned short* __restrict__ values, float* __restrict__ hT)
{
  int b0 = blockIdx.x * 16;
  int dir = blockIdx.y;
  int tid = threadIdx.x;
  int w = tid >> 6, lane = tid & 63, l15 = lane & 15, quad = lane >> 4;
  int h0 = w * 16;
  const unsigned short* wih = wihbf + dir * 16384;
  const unsigned short* whh = whhbf + dir * 16384;

  short8 bx[4][2], bh[4][2];
  float bias_v[4];
  #pragma unroll
  for (int g = 0; g < 4; ++g) {
    int row = g * 64 + h0 + l15;
    #pragma unroll
    for (int k = 0; k < 2; ++k) {
      bx[g][k] = __builtin_bit_cast(short8, *(const uint4v*)(wih + row * 64 + k * 32 + quad * 8));
      bh[g][k] = __builtin_bit_cast(short8, *(const uint4v*)(whh + row * 64 + k * 32 + quad * 8));
    }
    bias_v[g] = lbias[dir * 256 + g * 64 + h0 + l15];
  }

  __shared__ __align__(16) unsigned short xls[2][8][16 * 72];
  __shared__ __align__(16) unsigned short hist[8][16 * 72];
  for (int j = tid; j < 16 * 72; j += 256) hist[7][j] = 0;  // h_{-1} = 0

  int bl = tid >> 4, d4 = tid & 15;
  const unsigned short* xrow = x2bf + ((size_t)(b0 + bl) * TT) * 64 + d4 * 4;

  uint2 xr[8];
  #pragma unroll
  for (int k = 0; k < 8; ++k) {               // chunk 0
    int t = dir ? (TT - 1 - k) : k;
    xr[k] = *(const uint2*)(xrow + (size_t)t * 64);
  }
  #pragma unroll
  for (int k = 0; k < 8; ++k)
    *(uint2*)(&xls[0][k][bl * 72 + d4 * 4]) = xr[k];
  #pragma unroll
  for (int k = 0; k < 8; ++k) {               // chunk 1
    int s = 8 + k;
    int t = dir ? (TT - 1 - s) : s;
    xr[k] = *(const uint2*)(xrow + (size_t)t * 64);
  }
  __syncthreads();

  float cst[4] = {0.f, 0.f, 0.f, 0.f};
  for (int c = 0; c < 31; ++c) {
    int buf = c & 1;
    // ---- 8 steps, no vmem (step 247 is a dummy: written to hist[7], never dumped)
    #pragma unroll
    for (int sl = 0; sl < 8; ++sl) {
      int hp = (sl + 7) & 7;
      short8 ax0 = __builtin_bit_cast(short8, *(const uint4v*)(&xls[buf][sl][l15 * 72 + quad * 8]));
      short8 ax1 = __builtin_bit_cast(short8, *(const uint4v*)(&xls[buf][sl][l15 * 72 + 32 + quad * 8]));
      short8 ah0 = __builtin_bit_cast(short8, *(const uint4v*)(&hist[hp][l15 * 72 + quad * 8]));
      short8 ah1 = __builtin_bit_cast(short8, *(const uint4v*)(&hist[hp][l15 * 72 + 32 + quad * 8]));
      f32x4 aX[4], aH[4];
      #pragma unroll
      for (int g = 0; g < 4; ++g) {
        aX[g] = (f32x4){bias_v[g], bias_v[g], bias_v[g], bias_v[g]};
        aX[g] = __builtin_amdgcn_mfma_f32_16x16x32_bf16(ax0, bx[g][0], aX[g], 0, 0, 0);
        aX[g] = __builtin_amdgcn_mfma_f32_16x16x32_bf16(ax1, bx[g][1], aX[g], 0, 0, 0);
        aH[g] = (f32x4){0.f, 0.f, 0.f, 0.f};
        aH[g] = __builtin_amdgcn_mfma_f32_16x16x32_bf16(ah0, bh[g][0], aH[g], 0, 0, 0);
        aH[g] = __builtin_amdgcn_mfma_f32_16x16x32_bf16(ah1, bh[g][1], aH[g], 0, 0, 0);
      }
      #pragma unroll
      for (int r = 0; r < 4; ++r) {
        float ig = sigf(aX[0][r] + aH[0][r]);
        float fg = sigf(aX[1][r] + aH[1][r]);
        float gg = tanhff(aX[2][r] + aH[2][r]);
        float og = sigf(aX[3][r] + aH[3][r]);
        cst[r] = fg * cst[r] + ig * gg;
        float hh = og * tanhff(cst[r]);
        hist[sl][(quad * 4 + r) * 72 + h0 + l15] = bfr(hh);
        if (c == 30 && sl == 6) {             // global step 246 = last real step
          int bglob = b0 + quad * 4 + r;
          hT[((size_t)dir * BB + bglob) * 64 + h0 + l15] = hh;
        }
      }
      lds_barrier();
    }
    // ---- boundary: dump hist -> values (coalesced, fire-and-forget)
    uint4v dv[4];
    #pragma unroll
    for (int i = 0; i < 4; ++i) {
      int flat = i * 256 + tid;
      int sl = flat >> 7, wb = (flat >> 3) & 15, c8 = flat & 7;
      dv[i] = *(const uint4v*)(&hist[sl][wb * 72 + c8 * 8]);
    }
    #pragma unroll
    for (int i = 0; i < 4; ++i) {
      int flat = i * 256 + tid;
      int sl = flat >> 7, wb = (flat >> 3) & 15, c8 = flat & 7;
      int s = c * 8 + sl;
      if (s < TT) {
        int t = dir ? (TT - 1 - s) : s;
        *(uint4v*)(values + ((size_t)(b0 + wb) * TT + t) * D2 + dir * 64 + c8 * 8) = dv[i];
      }
    }
    if (c < 30) {
      // stage chunk c+1 x (regs loaded one chunk ago; wait sees no older stores)
      #pragma unroll
      for (int k = 0; k < 8; ++k)
        *(uint2*)(&xls[1 - buf][k][bl * 72 + d4 * 4]) = xr[k];
      // issue chunk c+2 loads (BEFORE next boundary's dump stores)
      #pragma unroll
      for (int k = 0; k < 8; ++k) {
        int s2 = (c + 2) * 8 + k;
        if (s2 > TT - 1) s2 = TT - 1;
        int t2 = dir ? (TT - 1 - s2) : s2;
        xr[k] = *(const uint2*)(xrow + (size_t)t2 * 64);
      }
    }
    lds_barrier();
  }
}

// ---------------- K3b: q2 = h_n @ W2^T + W2_b ----------------
__global__ __launch_bounds__(128) void k_q2(const float* __restrict__ hT,
    const float* __restrict__ W2, const float* __restrict__ W2b,
    float* __restrict__ q2)
{
  int b = blockIdx.x;
  int tid = threadIdx.x;
  __shared__ float4 hn4[32];
  ((float*)hn4)[tid] = hT[(size_t)b * 128 + tid];
  __syncthreads();
  const float4* w4 = (const float4*)(W2 + (size_t)tid * 128);
  float a = W2b[tid];
  #pragma unroll
  for (int j = 0; j < 32; ++j) {
    float4 w = w4[j]; float4 h = hn4[j];
    a += w.x * h.x + w.y * h.y + w.z * h.z + w.w * h.w;
  }
  q2[(size_t)b * 128 + tid] = a;
}

// ---------------- K4: score via MFMA ----------------
__global__ __launch_bounds__(256) void k_score_m(const unsigned short* __restrict__ vbf,
    const unsigned short* __restrict__ W1bf, const float* __restrict__ W1b,
    const float* __restrict__ q2, const unsigned short* __restrict__ Vbf,
    const float* __restrict__ Vb, float* __restrict__ score)
{
  int b = blockIdx.x, t0 = blockIdx.y * 64;
  int tid = threadIdx.x, w = tid >> 6, lane = tid & 63, l15 = lane & 15, quad = lane >> 4;
  __shared__ unsigned short us[64 * 136];
  const unsigned short* arow = vbf + ((size_t)b * TT + t0 + w * 16 + l15) * 128;
  short8 ax[4];
  #pragma unroll
  for (int ks = 0; ks < 4; ++ks)
    ax[ks] = __builtin_bit_cast(short8, *(const uint4v*)(arow + ks * 32 + quad * 8));
  #pragma unroll
  for (int nt = 0; nt < 8; ++nt) {
    int n = nt * 16 + l15;
    float base = W1b[n] + q2[(size_t)b * 128 + n];
    f32x4 acc = (f32x4){base, base, base, base};
    #pragma unroll
    for (int ks = 0; ks < 4; ++ks) {
      short8 bf = __builtin_bit_cast(short8,
          *(const uint4v*)(W1bf + (size_t)n * 128 + ks * 32 + quad * 8));
      acc = __builtin_amdgcn_mfma_f32_16x16x32_bf16(ax[ks], bf, acc, 0, 0, 0);
    }
    #pragma unroll
    for (int r = 0; r < 4; ++r)
      us[(w * 16 + quad * 4 + r) * 136 + nt * 16 + l15] = bfr(tanhff(acc[r]));
  }
  __syncthreads();
  short8 au[4];
  #pragma unroll
  for (int ks = 0; ks < 4; ++ks)
    au[ks] = __builtin_bit_cast(short8, *(const uint4v*)(&us[(w * 16 + l15) * 136 + ks * 32 + quad * 8]));
  for (int nt2 = 0; nt2 < 13; ++nt2) {
    int n = nt2 * 16 + l15;
    float b2 = (n < NTF) ? Vb[n] : 0.0f;
    f32x4 a2 = (f32x4){b2, b2, b2, b2};
    #pragma unroll
    for (int ks = 0; ks < 4; ++ks) {
      short8 bf = __builtin_bit_cast(short8,
          *(const uint4v*)(Vbf + (size_t)n * 128 + ks * 32 + quad * 8));
      a2 = __builtin_amdgcn_mfma_f32_16x16x32_bf16(au[ks], bf, a2, 0, 0, 0);
    }
    #pragma unroll
    for (int r = 0; r < 4; ++r) {
      int t = t0 + w * 16 + quad * 4 + r;
      if (t < TT && n < NTF) score[((size_t)b * TT + t) * NTF + n] = a2[r];
    }
  }
}

// ---------------- K5: softmax over t, 4x unrolled (stores unnorm exp + 1/sum) ----------------
__global__ __launch_bounds__(256) void k_softmax(float* __restrict__ score,
    float* __restrict__ sinv)
{
  int b = blockIdx.x;
  int n = threadIdx.x;
  if (n >= NTF) return;
  size_t base = (size_t)b * TT * NTF + n;
  float m0 = -1e30f, m1 = -1e30f, m2 = -1e30f, m3 = -1e30f;
  int t = 0;
  for (; t + 4 <= TT; t += 4) {
    float a = score[base + (size_t)t * NTF];
    float bb = score[base + (size_t)(t + 1) * NTF];
    float cc = score[base + (size_t)(t + 2) * NTF];
    float dd = score[base + (size_t)(t + 3) * NTF];
    m0 = fmaxf(m0, a); m1 = fmaxf(m1, bb); m2 = fmaxf(m2, cc); m3 = fmaxf(m3, dd);
  }
  for (; t < TT; ++t) m0 = fmaxf(m0, score[base + (size_t)t * NTF]);
  float m = fmaxf(fmaxf(m0, m1), fmaxf(m2, m3));
  float s0 = 0.f, s1 = 0.f, s2 = 0.f, s3 = 0.f;
  for (t = 0; t + 4 <= TT; t += 4) {
    float a = __expf(score[base + (size_t)t * NTF] - m);
    float bb = __expf(score[base + (size_t)(t + 1) * NTF] - m);
    float cc = __expf(score[base + (size_t)(t + 2) * NTF] - m);
    float dd = __expf(score[base + (size_t)(t + 3) * NTF] - m);
    score[base + (size_t)t * NTF] = a;
    score[base + (size_t)(t + 1) * NTF] = bb;
    score[base + (size_t)(t + 2) * NTF] = cc;
    score[base + (size_t)(t + 3) * NTF] = dd;
    s0 += a; s1 += bb; s2 += cc; s3 += dd;
  }
  for (; t < TT; ++t) {
    float e = __expf(score[base + (size_t)t * NTF] - m);
    score[base + (size_t)t * NTF] = e;
    s0 += e;
  }
  sinv[(size_t)b * NTF + n] = 1.0f / (s0 + s1 + s2 + s3);
}

// ---------------- K6: context via MFMA ----------------
__global__ __launch_bounds__(256) void k_ctx_m(const unsigned short* __restrict__ vbf,
    const float* __restrict__ score, const float* __restrict__ sinv,
    float* __restrict__ ctx)
{
  int b = blockIdx.x;
  int tid = threadIdx.x, w = tid >> 6, lane = tid & 63, l15 = lane & 15, quad = lane >> 4;
  __shared__ unsigned short ascore[208 * 40];
  __shared__ unsigned short bval[128 * 40];
  __shared__ float sls[208];
  for (int j = tid; j < 208; j += 256) sls[j] = (j < NTF) ? sinv[(size_t)b * NTF + j] : 0.0f;

  f32x4 acc[4][8];
  #pragma unroll
  for (int i = 0; i < 4; ++i)
    #pragma unroll
    for (int nt = 0; nt < 8; ++nt) acc[i][nt] = (f32x4){0.f, 0.f, 0.f, 0.f};

  for (int ch = 0; ch < 8; ++ch) {
    int tc = ch * 32;
    __syncthreads();
    for (int j = tid; j < 32 * 256; j += 256) {
      int tl = j >> 8, n = j & 255;
      if (n < 208) {
        int t = tc + tl;
        float v = (n < NTF && t < TT) ? score[((size_t)b * TT + t) * NTF + n] : 0.0f;
        ascore[n * 40 + tl] = bfr(v);
      }
    }
    for (int j = tid; j < 32 * 64; j += 256) {
      int tl = j >> 6, d2 = j & 63;
      int t = tc + tl;
      unsigned v = (t < TT) ? *(const unsigned*)(vbf + ((size_t)b * TT + t) * D2 + d2 * 2) : 0u;
      bval[(d2 * 2) * 40 + tl] = (unsigned short)(v & 0xffffu);
      bval[(d2 * 2 + 1) * 40 + tl] = (unsigned short)(v >> 16);
    }
    __syncthreads();
    short8 bv[8];
    #pragma unroll
    for (int nt = 0; nt < 8; ++nt)
      bv[nt] = __builtin_bit_cast(short8, *(const uint4v*)(&bval[(nt * 16 + l15) * 40 + quad * 8]));
    #pragma unroll
    for (int i = 0; i < 4; ++i) {
      int mt = w + 4 * i;
      if (mt < 13) {
        short8 au = __builtin_bit_cast(short8, *(const uint4v*)(&ascore[(mt * 16 + l15) * 40 + quad * 8]));
        #pragma unroll
        for (int nt = 0; nt < 8; ++nt)
          acc[i][nt] = __builtin_amdgcn_mfma_f32_16x16x32_bf16(au, bv[nt], acc[i][nt], 0, 0, 0);
      }
    }
  }
  #pragma unroll
  for (int i = 0; i < 4; ++i) {
    int mt = w + 4 * i;
    if (mt < 13) {
      #pragma unroll
      for (int r = 0; r < 4; ++r) {
        int n = mt * 16 + quad * 4 + r;
        if (n < NTF) {
          float rs = sls[n];
          #pragma unroll
          for (int nt = 0; nt < 8; ++nt) {
            int d = nt * 16 + l15;
            ctx[((size_t)b * NTF + n) * D2 + d] = acc[i][nt][r] * rs;
          }
        }
      }
    }
  }
}

// ---------------- K7: per-TF heads ----------------
__global__ __launch_bounds__(256) void k_heads(const float* __restrict__ ctx,
    const float* __restrict__ fc1w, const float* __restrict__ fc1b,
    const float* __restrict__ fc2w, const float* __restrict__ fc2b,
    float* __restrict__ out)
{
  int n = blockIdx.x;
  int bq = blockIdx.y;
  int tid = threadIdx.x;
  int o = tid & 63, w = tid >> 6;
  __shared__ float ctxs[4 * 128];
  float4 fr[32];
  const float4* fp = (const float4*)(fc1w + ((size_t)n * 64 + o) * 128);
  #pragma unroll
  for (int j = 0; j < 32; ++j) fr[j] = fp[j];
  float f1bv = fc1b[n * 64 + o];
  float f2 = fc2w[n * 64 + o];
  float f2b = fc2b[n];
  for (int i = 0; i < 16; ++i) {
    int bbase = bq * 64 + i * 4;
    __syncthreads();
    for (int j = tid; j < 512; j += 256) {
      int ww = j >> 7, k = j & 127;
      ctxs[j] = ctx[((size_t)(bbase + ww) * NTF + n) * D2 + k];
    }
    __syncthreads();
    float a = f1bv;
    const float4* c4 = (const float4*)(ctxs + w * 128);
    #pragma unroll
    for (int j = 0; j < 32; ++j) {
      float4 cv = c4[j];
      float4 fv = fr[j];
      a += cv.x * fv.x + cv.y * fv.y + cv.z * fv.z + cv.w * fv.w;
    }
    float part = fmaxf(a, 0.0f) * f2;
    #pragma unroll
    for (int off = 32; off > 0; off >>= 1)
      part += __shfl_down(part, off, 64);
    if (o == 0) out[(size_t)(bbase + w) * NTF + n] = part + f2b;
  }
}

extern "C" void kernel_launch(void* const* d_in, const int* in_sizes, int n_in,
                              void* d_out, int out_size, void* d_ws, size_t ws_size,
                              hipStream_t stream)
{
  const float* x    = (const float*)d_in[0];
  const float* c0w  = (const float*)d_in[1];
  const float* c0b  = (const float*)d_in[2];
  const float* g0   = (const float*)d_in[3];
  const float* be0  = (const float*)d_in[4];
  const float* m0   = (const float*)d_in[5];
  const float* v0   = (const float*)d_in[6];
  const float* c1w  = (const float*)d_in[7];
  const float* c1b  = (const float*)d_in[8];
  const float* g1   = (const float*)d_in[9];
  const float* be1  = (const float*)d_in[10];
  const float* m1   = (const float*)d_in[11];
  const float* v1   = (const float*)d_in[12];
  const float* wihf = (const float*)d_in[13];
  const float* whhf = (const float*)d_in[14];
  const float* bihf = (const float*)d_in[15];
  const float* bhhf = (const float*)d_in[16];
  const float* wihb = (const float*)d_in[17];
  const float* whhb = (const float*)d_in[18];
  const float* bihb = (const float*)d_in[19];
  const float* bhhb = (const float*)d_in[20];
  const float* W1w  = (const float*)d_in[21];
  const float* W1b  = (const float*)d_in[22];
  const float* W2w  = (const float*)d_in[23];
  const float* W2b  = (const float*)d_in[24];
  const float* Vw   = (const float*)d_in[25];
  const float* Vb   = (const float*)d_in[26];
  const float* f1w  = (const float*)d_in[27];
  const float* f1b  = (const float*)d_in[28];
  const float* f2w  = (const float*)d_in[29];
  const float* f2b  = (const float*)d_in[30];

  float* ws = (float*)d_ws;
  // layout (f32 offsets); p/x2bf overlap score (dead before k_score_m writes)
  float* score  = ws;                         // 25,292,800 f32
  float* p      = ws;                         // 8,323,072
  unsigned short* x2bf = (unsigned short*)(ws + 8323072);  // 8,093,696 bf16
  unsigned short* vbf  = (unsigned short*)(ws + 25292800); // 16,187,392 bf16 (+slack)
  float* hT     = ws + 33387520;              // 65,536
  float* q2     = ws + 33453056;              // 65,536
  float* sinv   = ws + 33518592;              // 102,400
  float* ctx    = ws + 33620992;              // 13,107,200 (ends 46,728,192)
  unsigned short* wbf0  = (unsigned short*)(ws + 46728192);  // 2048
  unsigned short* wbf1  = (unsigned short*)(ws + 46729216);  // 32768
  unsigned short* wihbf = (unsigned short*)(ws + 46745600);  // 32768
  unsigned short* whhbf = (unsigned short*)(ws + 46761984);  // 32768
  float* lbias          = ws + 46778368;                     // 512
  unsigned short* W1bf  = (unsigned short*)(ws + 46778880);  // 16384
  unsigned short* Vbf   = (unsigned short*)(ws + 46787072);  // 26624
  float* out    = (float*)d_out;

  k_cvt<<<dim3(128), 256, 0, stream>>>(c0w, c1w, wihf, whhf, wihb, whhb,
                                       bihf, bhhf, bihb, bhhb, W1w, Vw,
                                       wbf0, wbf1, wihbf, whhbf, lbias, W1bf, Vbf);
  k_conv0m<<<dim3(BB, 16), 256, 0, stream>>>(x, wbf0, c0b, g0, be0, m0, v0, p);
  k_conv1m<<<dim3(BB, 4), 256, 0, stream>>>(p, wbf1, c1b, g1, be1, m1, v1, x2bf);
  k_lstm_m<<<dim3(BB / 16, 2), 256, 0, stream>>>(x2bf, wihbf, whhbf, lbias, vbf, hT);
  k_q2<<<dim3(BB), 128, 0, stream>>>(hT, W2w, W2b, q2);
  k_score_m<<<dim3(BB, 4), 256, 0, stream>>>(vbf, W1bf, W1b, q2, Vbf, Vb, score);
  k_softmax<<<dim3(BB), 256, 0, stream>>>(score, sinv);
  k_ctx_m<<<dim3(BB), 256, 0, stream>>>(vbf, score, sinv, ctx);
  k_heads<<<dim3(NTF, 8), 256, 0, stream>>>(ctx, f1w, f1b, f2w, f2b, out);
}

// Round 11
// 601.861 us; speedup vs baseline: 1.6085x; 1.3247x over previous
//
#include <hip/hip_runtime.h>
#include <math.h>

#define BB 512
#define LL 1024
#define EMB 4
#define CC 64
#define NTF 200
#define TT 247      // seq len after conv1
#define LP 254      // after pool
#define D2 128

typedef __attribute__((ext_vector_type(8))) short short8;
typedef __attribute__((ext_vector_type(4))) float f32x4;
typedef __attribute__((ext_vector_type(4))) unsigned int uint4v;

// Fast nonlinearities: v_rcp_f32 (1 ulp) instead of IEEE division chain.
__device__ __forceinline__ float sigf(float x) {
  return __builtin_amdgcn_rcpf(1.0f + __expf(-x));
}
__device__ __forceinline__ float tanhff(float x) {
  return 1.0f - 2.0f * __builtin_amdgcn_rcpf(__expf(2.0f * x) + 1.0f);
}

// LDS-only barrier: 0xC07F = vmcnt(63)|expcnt(7)|lgkmcnt(0).
__device__ __forceinline__ void lds_barrier() {
  __builtin_amdgcn_s_waitcnt(0xC07F);
  __builtin_amdgcn_s_barrier();
}

// f32 -> bf16 round-to-nearest-even (finite inputs)
__device__ __forceinline__ unsigned short bfr(float f) {
  unsigned u = __builtin_bit_cast(unsigned, f);
  u += 0x7fffu + ((u >> 16) & 1u);
  return (unsigned short)(u >> 16);
}
__device__ __forceinline__ float b2f(unsigned short s) {
  return __builtin_bit_cast(float, (unsigned)s << 16);
}

// ---------------- K0: convert weights to bf16 in ws + lstm bias sums ----------------
__global__ __launch_bounds__(256) void k_cvt(const float* __restrict__ w0,
    const float* __restrict__ w1,
    const float* __restrict__ wihf, const float* __restrict__ whhf,
    const float* __restrict__ wihb, const float* __restrict__ whhb,
    const float* __restrict__ bihf, const float* __restrict__ bhhf,
    const float* __restrict__ bihb, const float* __restrict__ bhhb,
    const float* __restrict__ W1w, const float* __restrict__ Vw,
    unsigned short* __restrict__ wbf0, unsigned short* __restrict__ wbf1,
    unsigned short* __restrict__ wihbf, unsigned short* __restrict__ whhbf,
    float* __restrict__ lbias,
    unsigned short* __restrict__ W1bf, unsigned short* __restrict__ Vbf)
{
  int i = blockIdx.x * 256 + threadIdx.x;   // grid 128*256 = 32768
  if (i < 2048) wbf0[i] = bfr(w0[i]);
  if (i < 32768) wbf1[i] = bfr(w1[i]);
  if (i < 16384) {
    wihbf[i] = bfr(wihf[i]);
    wihbf[16384 + i] = bfr(wihb[i]);
    whhbf[i] = bfr(whhf[i]);
    whhbf[16384 + i] = bfr(whhb[i]);
    W1bf[i] = bfr(W1w[i]);
  }
  if (i < 26624) {                           // Vbf padded to 208 rows
    int row = i >> 7;
    Vbf[i] = (row < NTF) ? bfr(Vw[i]) : (unsigned short)0;
  }
  if (i < 256) {
    lbias[i] = bihf[i] + bhhf[i];
    lbias[256 + i] = bihb[i] + bhhb[i];
  }
}

// ---------------- K1: conv0 + BN + ReLU + maxpool(4), MFMA ----------------
__global__ __launch_bounds__(256) void k_conv0m(const float* __restrict__ x,
    const unsigned short* __restrict__ wbf0,
    const float* __restrict__ b0, const float* __restrict__ g0,
    const float* __restrict__ be0, const float* __restrict__ m0,
    const float* __restrict__ v0, float* __restrict__ p)
{
  int b = blockIdx.x, l0 = blockIdx.y * 64;
  __shared__ float xs[71 * 4];
  __shared__ float sc[64], sb[64];
  int tid = threadIdx.x;
  for (int j = tid; j < 71; j += 256) {
    int l = l0 + j;
    float4 xv = (l < LL) ? *(const float4*)(x + ((size_t)b * LL + l) * EMB)
                         : make_float4(0.f, 0.f, 0.f, 0.f);
    *(float4*)(xs + j * 4) = xv;
  }
  if (tid < 64) {
    float s = g0[tid] * rsqrtf(v0[tid] + 1e-5f);
    sc[tid] = s;
    sb[tid] = (b0[tid] - m0[tid]) * s + be0[tid];
  }
  __syncthreads();
  int w = tid >> 6, lane = tid & 63, nl = lane & 15, quad = lane >> 4;
  const float* ap = xs + (w * 16 + nl) * 4 + quad;
  short8 af;
  #pragma unroll
  for (int j = 0; j < 8; ++j) af[j] = (short)bfr(ap[j * 4]);
  f32x4 acc[4];
  #pragma unroll
  for (int nt = 0; nt < 4; ++nt) {
    short8 bf = __builtin_bit_cast(short8,
        *(const uint4v*)(wbf0 + ((nt * 16 + nl) * 32 + quad * 8)));
    acc[nt] = (f32x4){0.f, 0.f, 0.f, 0.f};
    acc[nt] = __builtin_amdgcn_mfma_f32_16x16x32_bf16(af, bf, acc[nt], 0, 0, 0);
  }
  int t = (l0 >> 2) + w * 4 + quad;
  if (t < LP) {
    #pragma unroll
    for (int nt = 0; nt < 4; ++nt) {
      int c = nt * 16 + nl;
      float scc = sc[c], sbc = sb[c];
      float mx = -1e30f;
      #pragma unroll
      for (int r = 0; r < 4; ++r) mx = fmaxf(mx, acc[nt][r] * scc + sbc);
      p[((size_t)b * LP + t) * CC + c] = fmaxf(mx, 0.0f);
    }
  }
}

// ---------------- K2: conv1 + BN + ReLU -> x2bf[b][t][c] (bf16), MFMA ----------------
__global__ __launch_bounds__(256) void k_conv1m(const float* __restrict__ p,
    const unsigned short* __restrict__ wbf1,
    const float* __restrict__ b1, const float* __restrict__ g1,
    const float* __restrict__ be1, const float* __restrict__ m1,
    const float* __restrict__ v1, unsigned short* __restrict__ x2bf)
{
  int b = blockIdx.x, t0 = blockIdx.y * 64;
  __shared__ float As[71 * 68];
  __shared__ float sc[64], sb[64];
  int tid = threadIdx.x;
  for (int j = tid; j < 71 * 64; j += 256) {
    int col = j >> 6, ci = j & 63;
    int t = t0 + col;
    As[col * 68 + ci] = (t < LP) ? p[((size_t)b * LP + t) * CC + ci] : 0.0f;
  }
  if (tid < 64) {
    float s = g1[tid] * rsqrtf(v1[tid] + 1e-5f);
    sc[tid] = s;
    sb[tid] = (b1[tid] - m1[tid]) * s + be1[tid];
  }
  __syncthreads();
  int w = tid >> 6, lane = tid & 63, nl = lane & 15, quad = lane >> 4;
  const float* ap = As + (w * 16 + nl) * 68;
  f32x4 acc[4];
  #pragma unroll
  for (int nt = 0; nt < 4; ++nt) acc[nt] = (f32x4){0.f, 0.f, 0.f, 0.f};
  for (int ks = 0; ks < 16; ++ks) {
    int ci = ks * 4 + quad;
    short8 af;
    #pragma unroll
    for (int j = 0; j < 8; ++j) af[j] = (short)bfr(ap[j * 68 + ci]);
    #pragma unroll
    for (int nt = 0; nt < 4; ++nt) {
      short8 bf = __builtin_bit_cast(short8,
          *(const uint4v*)(wbf1 + ((size_t)(nt * 16 + nl) * 512 + ci * 8)));
      acc[nt] = __builtin_amdgcn_mfma_f32_16x16x32_bf16(af, bf, acc[nt], 0, 0, 0);
    }
  }
  #pragma unroll
  for (int nt = 0; nt < 4; ++nt) {
    int c = nt * 16 + nl;
    float scc = sc[c], sbc = sb[c];
    #pragma unroll
    for (int r = 0; r < 4; ++r) {
      int t = t0 + w * 16 + quad * 4 + r;
      if (t < TT)
        x2bf[((size_t)b * TT + t) * CC + c] = bfr(fmaxf(acc[nt][r] * scc + sbc, 0.0f));
    }
  }
}

// ---------------- K3: bi-LSTM via MFMA, chunked I/O ----------------
__global__ __launch_bounds__(256) void k_lstm_m(const unsigned short* __restrict__ x2bf,
    const unsigned short* __restrict__ wihbf, const unsigned short* __restrict__ whhbf,
    const float* __restrict__ lbias,
    unsigned short* __restrict__ values, float* __restrict__ hT)
{
  int b0 = blockIdx.x * 16;
  int dir = blockIdx.y;
  int tid = threadIdx.x;
  int w = tid >> 6, lane = tid & 63, l15 = lane & 15, quad = lane >> 4;
  int h0 = w * 16;
  const unsigned short* wih = wihbf + dir * 16384;
  const unsigned short* whh = whhbf + dir * 16384;

  short8 bx[4][2], bh[4][2];
  float bias_v[4];
  #pragma unroll
  for (int g = 0; g < 4; ++g) {
    int row = g * 64 + h0 + l15;
    #pragma unroll
    for (int k = 0; k < 2; ++k) {
      bx[g][k] = __builtin_bit_cast(short8, *(const uint4v*)(wih + row * 64 + k * 32 + quad * 8));
      bh[g][k] = __builtin_bit_cast(short8, *(const uint4v*)(whh + row * 64 + k * 32 + quad * 8));
    }
    bias_v[g] = lbias[dir * 256 + g * 64 + h0 + l15];
  }

  __shared__ __align__(16) unsigned short xls[2][8][16 * 72];
  __shared__ __align__(16) unsigned short hist[8][16 * 72];
  for (int j = tid; j < 16 * 72; j += 256) hist[7][j] = 0;  // h_{-1} = 0

  int bl = tid >> 4, d4 = tid & 15;
  const unsigned short* xrow = x2bf + ((size_t)(b0 + bl) * TT) * 64 + d4 * 4;

  uint2 xr[8];
  #pragma unroll
  for (int k = 0; k < 8; ++k) {               // chunk 0
    int t = dir ? (TT - 1 - k) : k;
    xr[k] = *(const uint2*)(xrow + (size_t)t * 64);
  }
  #pragma unroll
  for (int k = 0; k < 8; ++k)
    *(uint2*)(&xls[0][k][bl * 72 + d4 * 4]) = xr[k];
  #pragma unroll
  for (int k = 0; k < 8; ++k) {               // chunk 1
    int s = 8 + k;
    int t = dir ? (TT - 1 - s) : s;
    xr[k] = *(const uint2*)(xrow + (size_t)t * 64);
  }
  __syncthreads();

  float cst[4] = {0.f, 0.f, 0.f, 0.f};
  for (int c = 0; c < 31; ++c) {
    int buf = c & 1;
    #pragma unroll
    for (int sl = 0; sl < 8; ++sl) {
      int hp = (sl + 7) & 7;
      short8 ax0 = __builtin_bit_cast(short8, *(const uint4v*)(&xls[buf][sl][l15 * 72 + quad * 8]));
      short8 ax1 = __builtin_bit_cast(short8, *(const uint4v*)(&xls[buf][sl][l15 * 72 + 32 + quad * 8]));
      short8 ah0 = __builtin_bit_cast(short8, *(const uint4v*)(&hist[hp][l15 * 72 + quad * 8]));
      short8 ah1 = __builtin_bit_cast(short8, *(const uint4v*)(&hist[hp][l15 * 72 + 32 + quad * 8]));
      f32x4 aX[4], aH[4];
      #pragma unroll
      for (int g = 0; g < 4; ++g) {
        aX[g] = (f32x4){bias_v[g], bias_v[g], bias_v[g], bias_v[g]};
        aX[g] = __builtin_amdgcn_mfma_f32_16x16x32_bf16(ax0, bx[g][0], aX[g], 0, 0, 0);
        aX[g] = __builtin_amdgcn_mfma_f32_16x16x32_bf16(ax1, bx[g][1], aX[g], 0, 0, 0);
        aH[g] = (f32x4){0.f, 0.f, 0.f, 0.f};
        aH[g] = __builtin_amdgcn_mfma_f32_16x16x32_bf16(ah0, bh[g][0], aH[g], 0, 0, 0);
        aH[g] = __builtin_amdgcn_mfma_f32_16x16x32_bf16(ah1, bh[g][1], aH[g], 0, 0, 0);
      }
      #pragma unroll
      for (int r = 0; r < 4; ++r) {
        float ig = sigf(aX[0][r] + aH[0][r]);
        float fg = sigf(aX[1][r] + aH[1][r]);
        float gg = tanhff(aX[2][r] + aH[2][r]);
        float og = sigf(aX[3][r] + aH[3][r]);
        cst[r] = fg * cst[r] + ig * gg;
        float hh = og * tanhff(cst[r]);
        hist[sl][(quad * 4 + r) * 72 + h0 + l15] = bfr(hh);
        if (c == 30 && sl == 6) {             // global step 246 = last real step
          int bglob = b0 + quad * 4 + r;
          hT[((size_t)dir * BB + bglob) * 64 + h0 + l15] = hh;
        }
      }
      lds_barrier();
    }
    // ---- boundary: dump hist -> values (coalesced, fire-and-forget)
    uint4v dv[4];
    #pragma unroll
    for (int i = 0; i < 4; ++i) {
      int flat = i * 256 + tid;
      int sl = flat >> 7, wb = (flat >> 3) & 15, c8 = flat & 7;
      dv[i] = *(const uint4v*)(&hist[sl][wb * 72 + c8 * 8]);
    }
    #pragma unroll
    for (int i = 0; i < 4; ++i) {
      int flat = i * 256 + tid;
      int sl = flat >> 7, wb = (flat >> 3) & 15, c8 = flat & 7;
      int s = c * 8 + sl;
      if (s < TT) {
        int t = dir ? (TT - 1 - s) : s;
        *(uint4v*)(values + ((size_t)(b0 + wb) * TT + t) * D2 + dir * 64 + c8 * 8) = dv[i];
      }
    }
    if (c < 30) {
      #pragma unroll
      for (int k = 0; k < 8; ++k)
        *(uint2*)(&xls[1 - buf][k][bl * 72 + d4 * 4]) = xr[k];
      #pragma unroll
      for (int k = 0; k < 8; ++k) {
        int s2 = (c + 2) * 8 + k;
        if (s2 > TT - 1) s2 = TT - 1;
        int t2 = dir ? (TT - 1 - s2) : s2;
        xr[k] = *(const uint2*)(xrow + (size_t)t2 * 64);
      }
    }
    lds_barrier();
  }
}

// ---------------- K3b: q2 = h_n @ W2^T + W2_b ----------------
__global__ __launch_bounds__(128) void k_q2(const float* __restrict__ hT,
    const float* __restrict__ W2, const float* __restrict__ W2b,
    float* __restrict__ q2)
{
  int b = blockIdx.x;
  int tid = threadIdx.x;
  __shared__ float4 hn4[32];
  ((float*)hn4)[tid] = hT[(size_t)b * 128 + tid];
  __syncthreads();
  const float4* w4 = (const float4*)(W2 + (size_t)tid * 128);
  float a = W2b[tid];
  #pragma unroll
  for (int j = 0; j < 32; ++j) {
    float4 w = w4[j]; float4 h = hn4[j];
    a += w.x * h.x + w.y * h.y + w.z * h.z + w.w * h.w;
  }
  q2[(size_t)b * 128 + tid] = a;
}

// ---------------- K4: score via MFMA -> scoreT[b][n][t] bf16 (transposed) ----------------
__global__ __launch_bounds__(256) void k_score_m(const unsigned short* __restrict__ vbf,
    const unsigned short* __restrict__ W1bf, const float* __restrict__ W1b,
    const float* __restrict__ q2, const unsigned short* __restrict__ Vbf,
    const float* __restrict__ Vb, unsigned short* __restrict__ scoreT)
{
  int b = blockIdx.x, t0 = blockIdx.y * 64;
  int tid = threadIdx.x, w = tid >> 6, lane = tid & 63, l15 = lane & 15, quad = lane >> 4;
  __shared__ unsigned short us[64 * 136];
  __shared__ unsigned short sc2[64 * 213];   // [t-local][n], odd-ish stride
  const unsigned short* arow = vbf + ((size_t)b * TT + t0 + w * 16 + l15) * 128;
  short8 ax[4];
  #pragma unroll
  for (int ks = 0; ks < 4; ++ks)
    ax[ks] = __builtin_bit_cast(short8, *(const uint4v*)(arow + ks * 32 + quad * 8));
  #pragma unroll
  for (int nt = 0; nt < 8; ++nt) {
    int n = nt * 16 + l15;
    float base = W1b[n] + q2[(size_t)b * 128 + n];
    f32x4 acc = (f32x4){base, base, base, base};
    #pragma unroll
    for (int ks = 0; ks < 4; ++ks) {
      short8 bf = __builtin_bit_cast(short8,
          *(const uint4v*)(W1bf + (size_t)n * 128 + ks * 32 + quad * 8));
      acc = __builtin_amdgcn_mfma_f32_16x16x32_bf16(ax[ks], bf, acc, 0, 0, 0);
    }
    #pragma unroll
    for (int r = 0; r < 4; ++r)
      us[(w * 16 + quad * 4 + r) * 136 + nt * 16 + l15] = bfr(tanhff(acc[r]));
  }
  __syncthreads();
  short8 au[4];
  #pragma unroll
  for (int ks = 0; ks < 4; ++ks)
    au[ks] = __builtin_bit_cast(short8, *(const uint4v*)(&us[(w * 16 + l15) * 136 + ks * 32 + quad * 8]));
  for (int nt2 = 0; nt2 < 13; ++nt2) {
    int n = nt2 * 16 + l15;
    float b2 = (n < NTF) ? Vb[n] : 0.0f;
    f32x4 a2 = (f32x4){b2, b2, b2, b2};
    #pragma unroll
    for (int ks = 0; ks < 4; ++ks) {
      short8 bf = __builtin_bit_cast(short8,
          *(const uint4v*)(Vbf + (size_t)n * 128 + ks * 32 + quad * 8));
      a2 = __builtin_amdgcn_mfma_f32_16x16x32_bf16(au[ks], bf, a2, 0, 0, 0);
    }
    #pragma unroll
    for (int r = 0; r < 4; ++r) {
      int tl = w * 16 + quad * 4 + r;
      sc2[tl * 213 + n] = bfr(a2[r]);
    }
  }
  __syncthreads();
  // transposed write-out: coalesced 32B chunks per thread
  int tg = tid & 3;
  #pragma unroll
  for (int pp = 0; pp < 4; ++pp) {
    int nrow = pp * 64 + (tid >> 2);
    if (nrow < NTF) {
      unsigned uu[8];
      #pragma unroll
      for (int k2 = 0; k2 < 8; ++k2) {
        unsigned lo = sc2[(tg * 16 + k2 * 2) * 213 + nrow];
        unsigned hi = sc2[(tg * 16 + k2 * 2 + 1) * 213 + nrow];
        uu[k2] = lo | (hi << 16);
      }
      size_t dst = ((size_t)b * 208 + nrow) * 256 + t0 + tg * 16;
      *(uint4v*)(scoreT + dst) = (uint4v){uu[0], uu[1], uu[2], uu[3]};
      *(uint4v*)(scoreT + dst + 8) = (uint4v){uu[4], uu[5], uu[6], uu[7]};
    }
  }
}

// ---------------- K5: softmax over t, row-wise on scoreT (in-place exp, bf16) ----------------
// 4 threads per (b,n) row; contiguous t reads/writes; shuffle-combine width 4.
__global__ __launch_bounds__(256) void k_softmax(unsigned short* __restrict__ scoreT,
    float* __restrict__ sinv)
{
  int b = blockIdx.x, nc = blockIdx.y;
  int tid = threadIdx.x;
  int n = nc * 64 + (tid >> 2), tg = tid & 3;
  if (n >= NTF) return;
  unsigned short* row = scoreT + ((size_t)b * 208 + n) * 256 + tg * 64;
  uint4v ld[8];
  #pragma unroll
  for (int i = 0; i < 8; ++i) ld[i] = *(const uint4v*)(row + i * 8);
  float m = -1e30f;
  #pragma unroll
  for (int i = 0; i < 8; ++i) {
    #pragma unroll
    for (int u = 0; u < 4; ++u) {
      unsigned xv = ld[i][u];
      int t0 = tg * 64 + i * 8 + u * 2;
      float a = __builtin_bit_cast(float, xv << 16);
      float c = __builtin_bit_cast(float, xv & 0xffff0000u);
      if (t0 < TT) m = fmaxf(m, a);
      if (t0 + 1 < TT) m = fmaxf(m, c);
    }
  }
  m = fmaxf(m, __shfl_xor(m, 1, 64));
  m = fmaxf(m, __shfl_xor(m, 2, 64));
  float s = 0.0f;
  #pragma unroll
  for (int i = 0; i < 8; ++i) {
    uint4v ov;
    #pragma unroll
    for (int u = 0; u < 4; ++u) {
      unsigned xv = ld[i][u];
      int t0 = tg * 64 + i * 8 + u * 2;
      float a = __builtin_bit_cast(float, xv << 16);
      float c = __builtin_bit_cast(float, xv & 0xffff0000u);
      float ea = (t0 < TT) ? __expf(a - m) : 0.0f;
      float ec = (t0 + 1 < TT) ? __expf(c - m) : 0.0f;
      s += ea + ec;
      ov[u] = (unsigned)bfr(ea) | ((unsigned)bfr(ec) << 16);
    }
    *(uint4v*)(row + i * 8) = ov;
  }
  s += __shfl_xor(s, 1, 64);
  s += __shfl_xor(s, 2, 64);
  if (tg == 0) sinv[(size_t)b * NTF + n] = __builtin_amdgcn_rcpf(s);
}

// ---------------- K6: context via MFMA; A-frags direct from scoreT, B from LDS vT ----------------
// Block per b. values transposed ONCE into LDS (stride 264 shorts: 16B-aligned rows).
// Per m-tile: acc[8]+af[8] = 64 VGPR live -> no spills.
__global__ __launch_bounds__(256) void k_ctx_m(const unsigned short* __restrict__ vbf,
    const unsigned short* __restrict__ scoreT, const float* __restrict__ sinv,
    float* __restrict__ ctx)
{
  int b = blockIdx.x;
  int tid = threadIdx.x, w = tid >> 6, lane = tid & 63, l15 = lane & 15, quad = lane >> 4;
  __shared__ __align__(16) unsigned short vt[128 * 264];  // [d][t]
  __shared__ float sls[208];
  // stage values transposed: 247*64 uints, coalesced reads, one-time scatter writes
  for (int flat = tid; flat < 247 * 64; flat += 256) {
    int t = flat >> 6, dp = flat & 63;
    unsigned v = *(const unsigned*)(vbf + ((size_t)b * TT + t) * D2 + dp * 2);
    vt[(dp * 2) * 264 + t] = (unsigned short)(v & 0xffffu);
    vt[(dp * 2 + 1) * 264 + t] = (unsigned short)(v >> 16);
  }
  for (int j = tid; j < 128 * 9; j += 256) {   // zero t-pad 247..255
    int d = j / 9, t = 247 + (j % 9);
    vt[d * 264 + t] = 0;
  }
  for (int j = tid; j < 208; j += 256) sls[j] = (j < NTF) ? sinv[(size_t)b * NTF + j] : 0.0f;
  __syncthreads();

  const unsigned short* abase = scoreT + (size_t)b * 208 * 256;
  for (int mi = 0; mi < 4; ++mi) {
    int mt = w + 4 * mi;
    if (mt >= 13) continue;
    const unsigned short* arow = abase + (size_t)(mt * 16 + l15) * 256;
    short8 af[8];
    #pragma unroll
    for (int ks = 0; ks < 8; ++ks)
      af[ks] = __builtin_bit_cast(short8, *(const uint4v*)(arow + ks * 32 + quad * 8));
    f32x4 acc[8];
    #pragma unroll
    for (int dt = 0; dt < 8; ++dt) {
      acc[dt] = (f32x4){0.f, 0.f, 0.f, 0.f};
      #pragma unroll
      for (int ks = 0; ks < 8; ++ks) {
        short8 bf = __builtin_bit_cast(short8,
            *(const uint4v*)(&vt[(dt * 16 + l15) * 264 + ks * 32 + quad * 8]));
        acc[dt] = __builtin_amdgcn_mfma_f32_16x16x32_bf16(af[ks], bf, acc[dt], 0, 0, 0);
      }
    }
    #pragma unroll
    for (int r = 0; r < 4; ++r) {
      int n = mt * 16 + quad * 4 + r;
      if (n < NTF) {
        float rs = sls[n];
        #pragma unroll
        for (int dt = 0; dt < 8; ++dt)
          ctx[((size_t)b * NTF + n) * D2 + dt * 16 + l15] = acc[dt][r] * rs;
      }
    }
  }
}

// ---------------- K7: per-TF heads ----------------
__global__ __launch_bounds__(256) void k_heads(const float* __restrict__ ctx,
    const float* __restrict__ fc1w, const float* __restrict__ fc1b,
    const float* __restrict__ fc2w, const float* __restrict__ fc2b,
    float* __restrict__ out)
{
  int n = blockIdx.x;
  int bq = blockIdx.y;
  int tid = threadIdx.x;
  int o = tid & 63, w = tid >> 6;
  __shared__ float ctxs[4 * 128];
  float4 fr[32];
  const float4* fp = (const float4*)(fc1w + ((size_t)n * 64 + o) * 128);
  #pragma unroll
  for (int j = 0; j < 32; ++j) fr[j] = fp[j];
  float f1bv = fc1b[n * 64 + o];
  float f2 = fc2w[n * 64 + o];
  float f2b = fc2b[n];
  for (int i = 0; i < 16; ++i) {
    int bbase = bq * 64 + i * 4;
    __syncthreads();
    for (int j = tid; j < 512; j += 256) {
      int ww = j >> 7, k = j & 127;
      ctxs[j] = ctx[((size_t)(bbase + ww) * NTF + n) * D2 + k];
    }
    __syncthreads();
    float a = f1bv;
    const float4* c4 = (const float4*)(ctxs + w * 128);
    #pragma unroll
    for (int j = 0; j < 32; ++j) {
      float4 cv = c4[j];
      float4 fv = fr[j];
      a += cv.x * fv.x + cv.y * fv.y + cv.z * fv.z + cv.w * fv.w;
    }
    float part = fmaxf(a, 0.0f) * f2;
    #pragma unroll
    for (int off = 32; off > 0; off >>= 1)
      part += __shfl_down(part, off, 64);
    if (o == 0) out[(size_t)(bbase + w) * NTF + n] = part + f2b;
  }
}

extern "C" void kernel_launch(void* const* d_in, const int* in_sizes, int n_in,
                              void* d_out, int out_size, void* d_ws, size_t ws_size,
                              hipStream_t stream)
{
  const float* x    = (const float*)d_in[0];
  const float* c0w  = (const float*)d_in[1];
  const float* c0b  = (const float*)d_in[2];
  const float* g0   = (const float*)d_in[3];
  const float* be0  = (const float*)d_in[4];
  const float* m0   = (const float*)d_in[5];
  const float* v0   = (const float*)d_in[6];
  const float* c1w  = (const float*)d_in[7];
  const float* c1b  = (const float*)d_in[8];
  const float* g1   = (const float*)d_in[9];
  const float* be1  = (const float*)d_in[10];
  const float* m1   = (const float*)d_in[11];
  const float* v1   = (const float*)d_in[12];
  const float* wihf = (const float*)d_in[13];
  const float* whhf = (const float*)d_in[14];
  const float* bihf = (const float*)d_in[15];
  const float* bhhf = (const float*)d_in[16];
  const float* wihb = (const float*)d_in[17];
  const float* whhb = (const float*)d_in[18];
  const float* bihb = (const float*)d_in[19];
  const float* bhhb = (const float*)d_in[20];
  const float* W1w  = (const float*)d_in[21];
  const float* W1b  = (const float*)d_in[22];
  const float* W2w  = (const float*)d_in[23];
  const float* W2b  = (const float*)d_in[24];
  const float* Vw   = (const float*)d_in[25];
  const float* Vb   = (const float*)d_in[26];
  const float* f1w  = (const float*)d_in[27];
  const float* f1b  = (const float*)d_in[28];
  const float* f2w  = (const float*)d_in[29];
  const float* f2b  = (const float*)d_in[30];

  float* ws = (float*)d_ws;
  // layout (f32 offsets). scoreT (bf16 [b][208][256] = 13,631,488 f32-slots) at ws[0]
  // overlaps p [0..8.3M) and x2bf [8.3M..12.4M) -- both dead before k_score_m.
  unsigned short* scoreT = (unsigned short*)ws;
  float* p      = ws;                         // 8,323,072
  unsigned short* x2bf = (unsigned short*)(ws + 8323072);  // 8,093,696 bf16
  unsigned short* vbf  = (unsigned short*)(ws + 25292800); // 16,187,392 bf16
  float* hT     = ws + 33387520;              // 65,536
  float* q2     = ws + 33453056;              // 65,536
  float* sinv   = ws + 33518592;              // 102,400
  float* ctx    = ws + 33620992;              // 13,107,200 (ends 46,728,192)
  unsigned short* wbf0  = (unsigned short*)(ws + 46728192);  // 2048
  unsigned short* wbf1  = (unsigned short*)(ws + 46729216);  // 32768
  unsigned short* wihbf = (unsigned short*)(ws + 46745600);  // 32768
  unsigned short* whhbf = (unsigned short*)(ws + 46761984);  // 32768
  float* lbias          = ws + 46778368;                     // 512
  unsigned short* W1bf  = (unsigned short*)(ws + 46778880);  // 16384
  unsigned short* Vbf   = (unsigned short*)(ws + 46787072);  // 26624
  float* out    = (float*)d_out;

  k_cvt<<<dim3(128), 256, 0, stream>>>(c0w, c1w, wihf, whhf, wihb, whhb,
                                       bihf, bhhf, bihb, bhhb, W1w, Vw,
                                       wbf0, wbf1, wihbf, whhbf, lbias, W1bf, Vbf);
  k_conv0m<<<dim3(BB, 16), 256, 0, stream>>>(x, wbf0, c0b, g0, be0, m0, v0, p);
  k_conv1m<<<dim3(BB, 4), 256, 0, stream>>>(p, wbf1, c1b, g1, be1, m1, v1, x2bf);
  k_lstm_m<<<dim3(BB / 16, 2), 256, 0, stream>>>(x2bf, wihbf, whhbf, lbias, vbf, hT);
  k_q2<<<dim3(BB), 128, 0, stream>>>(hT, W2w, W2b, q2);
  k_score_m<<<dim3(BB, 4), 256, 0, stream>>>(vbf, W1bf, W1b, q2, Vbf, Vb, scoreT);
  k_softmax<<<dim3(BB, 4), 256, 0, stream>>>(scoreT, sinv);
  k_ctx_m<<<dim3(BB), 256, 0, stream>>>(vbf, scoreT, sinv, ctx);
  k_heads<<<dim3(NTF, 8), 256, 0, stream>>>(ctx, f1w, f1b, f2w, f2b, out);
}

// Round 12
// 514.868 us; speedup vs baseline: 1.8803x; 1.1690x over previous
//
#include <hip/hip_runtime.h>
#include <math.h>

#define BB 512
#define LL 1024
#define EMB 4
#define CC 64
#define NTF 200
#define TT 247      // seq len after conv1
#define LP 254      // after pool
#define D2 128

typedef __attribute__((ext_vector_type(8))) short short8;
typedef __attribute__((ext_vector_type(4))) float f32x4;
typedef __attribute__((ext_vector_type(4))) unsigned int uint4v;

// Fast nonlinearities: v_rcp_f32 (1 ulp) instead of IEEE division chain.
__device__ __forceinline__ float sigf(float x) {
  return __builtin_amdgcn_rcpf(1.0f + __expf(-x));
}
__device__ __forceinline__ float tanhff(float x) {
  return 1.0f - 2.0f * __builtin_amdgcn_rcpf(__expf(2.0f * x) + 1.0f);
}

// LDS-only barrier: 0xC07F = vmcnt(63)|expcnt(7)|lgkmcnt(0).
__device__ __forceinline__ void lds_barrier() {
  __builtin_amdgcn_s_waitcnt(0xC07F);
  __builtin_amdgcn_s_barrier();
}

// f32 -> bf16 round-to-nearest-even (finite inputs)
__device__ __forceinline__ unsigned short bfr(float f) {
  unsigned u = __builtin_bit_cast(unsigned, f);
  u += 0x7fffu + ((u >> 16) & 1u);
  return (unsigned short)(u >> 16);
}

// ---------------- K0: weight conversions ----------------
// grid 6400*256 covers fc1w (1,638,400). wbf1r is w1 REORDERED to [co][k][ci].
__global__ __launch_bounds__(256) void k_cvt(const float* __restrict__ w0,
    const float* __restrict__ w1,
    const float* __restrict__ wihf, const float* __restrict__ whhf,
    const float* __restrict__ wihb, const float* __restrict__ whhb,
    const float* __restrict__ bihf, const float* __restrict__ bhhf,
    const float* __restrict__ bihb, const float* __restrict__ bhhb,
    const float* __restrict__ W1w, const float* __restrict__ Vw,
    const float* __restrict__ f1w,
    unsigned short* __restrict__ wbf0, unsigned short* __restrict__ wbf1r,
    unsigned short* __restrict__ wihbf, unsigned short* __restrict__ whhbf,
    float* __restrict__ lbias,
    unsigned short* __restrict__ W1bf, unsigned short* __restrict__ Vbf,
    unsigned short* __restrict__ f1bf)
{
  int i = blockIdx.x * 256 + threadIdx.x;
  if (i < 2048) wbf0[i] = bfr(w0[i]);
  if (i < 32768) {                           // dst [co][k][ci] <- src [co][ci][k]
    int co = i >> 9, k = (i >> 6) & 7, ci = i & 63;
    wbf1r[i] = bfr(w1[co * 512 + ci * 8 + k]);
  }
  if (i < 16384) {
    wihbf[i] = bfr(wihf[i]);
    wihbf[16384 + i] = bfr(wihb[i]);
    whhbf[i] = bfr(whhf[i]);
    whhbf[16384 + i] = bfr(whhb[i]);
    W1bf[i] = bfr(W1w[i]);
  }
  if (i < 26624) {                           // Vbf padded to 208 rows
    int row = i >> 7;
    Vbf[i] = (row < NTF) ? bfr(Vw[i]) : (unsigned short)0;
  }
  if (i < 256) {
    lbias[i] = bihf[i] + bhhf[i];
    lbias[256 + i] = bihb[i] + bhhb[i];
  }
  if (i < 1638400) f1bf[i] = bfr(f1w[i]);    // [n][o][k] flat
}

// ---------------- K1: conv0 + BN + ReLU + maxpool(4), MFMA -> pbf (bf16) ----------------
__global__ __launch_bounds__(256) void k_conv0m(const float* __restrict__ x,
    const unsigned short* __restrict__ wbf0,
    const float* __restrict__ b0, const float* __restrict__ g0,
    const float* __restrict__ be0, const float* __restrict__ m0,
    const float* __restrict__ v0, unsigned short* __restrict__ pbf)
{
  int b = blockIdx.x, l0 = blockIdx.y * 64;
  __shared__ float xs[71 * 4];
  __shared__ float sc[64], sb[64];
  int tid = threadIdx.x;
  for (int j = tid; j < 71; j += 256) {
    int l = l0 + j;
    float4 xv = (l < LL) ? *(const float4*)(x + ((size_t)b * LL + l) * EMB)
                         : make_float4(0.f, 0.f, 0.f, 0.f);
    *(float4*)(xs + j * 4) = xv;
  }
  if (tid < 64) {
    float s = g0[tid] * rsqrtf(v0[tid] + 1e-5f);
    sc[tid] = s;
    sb[tid] = (b0[tid] - m0[tid]) * s + be0[tid];
  }
  __syncthreads();
  int w = tid >> 6, lane = tid & 63, nl = lane & 15, quad = lane >> 4;
  const float* ap = xs + (w * 16 + nl) * 4 + quad;
  short8 af;
  #pragma unroll
  for (int j = 0; j < 8; ++j) af[j] = (short)bfr(ap[j * 4]);
  f32x4 acc[4];
  #pragma unroll
  for (int nt = 0; nt < 4; ++nt) {
    short8 bf = __builtin_bit_cast(short8,
        *(const uint4v*)(wbf0 + ((nt * 16 + nl) * 32 + quad * 8)));
    acc[nt] = (f32x4){0.f, 0.f, 0.f, 0.f};
    acc[nt] = __builtin_amdgcn_mfma_f32_16x16x32_bf16(af, bf, acc[nt], 0, 0, 0);
  }
  int t = (l0 >> 2) + w * 4 + quad;
  if (t < LP) {
    #pragma unroll
    for (int nt = 0; nt < 4; ++nt) {
      int c = nt * 16 + nl;
      float scc = sc[c], sbc = sb[c];
      float mx = -1e30f;
      #pragma unroll
      for (int r = 0; r < 4; ++r) mx = fmaxf(mx, acc[nt][r] * scc + sbc);
      pbf[((size_t)b * LP + t) * CC + c] = bfr(fmaxf(mx, 0.0f));
    }
  }
}

// ---------------- K2: conv1 as 8 shifted GEMMs (bf16 p, reordered weights) ----------------
// out[t][co] = sum_k sum_ci p[t+k][ci]*w1[co][ci,k]. Per shift k: A rows contiguous
// in ci -> direct b128 LDS frags (stride 72 shorts: 16B-aligned, 2-way banks=free).
__global__ __launch_bounds__(256) void k_conv1m(const unsigned short* __restrict__ pbf,
    const unsigned short* __restrict__ wbf1r,
    const float* __restrict__ b1, const float* __restrict__ g1,
    const float* __restrict__ be1, const float* __restrict__ m1,
    const float* __restrict__ v1, unsigned short* __restrict__ x2bf)
{
  int b = blockIdx.x, t0 = blockIdx.y * 64;
  __shared__ __align__(16) unsigned short ps[71 * 72];
  __shared__ float sc[64], sb[64];
  int tid = threadIdx.x;
  for (int j = tid; j < 71 * 32; j += 256) {
    int tl = j >> 5, cu = j & 31;
    int t = t0 + tl;
    unsigned v = (t < LP) ? *(const unsigned*)(pbf + ((size_t)b * LP + t) * CC + cu * 2) : 0u;
    *(unsigned*)(&ps[tl * 72 + cu * 2]) = v;
  }
  if (tid < 64) {
    float s = g1[tid] * rsqrtf(v1[tid] + 1e-5f);
    sc[tid] = s;
    sb[tid] = (b1[tid] - m1[tid]) * s + be1[tid];
  }
  __syncthreads();
  int w = tid >> 6, lane = tid & 63, nl = lane & 15, quad = lane >> 4;
  int tlb = w * 16 + nl;
  f32x4 acc[4];
  #pragma unroll
  for (int nt = 0; nt < 4; ++nt) acc[nt] = (f32x4){0.f, 0.f, 0.f, 0.f};
  #pragma unroll
  for (int k8 = 0; k8 < 8; ++k8) {
    short8 af0 = __builtin_bit_cast(short8,
        *(const uint4v*)(&ps[(tlb + k8) * 72 + 0 + quad * 8]));
    short8 af1 = __builtin_bit_cast(short8,
        *(const uint4v*)(&ps[(tlb + k8) * 72 + 32 + quad * 8]));
    #pragma unroll
    for (int nt = 0; nt < 4; ++nt) {
      int co = nt * 16 + nl;
      short8 bf0 = __builtin_bit_cast(short8,
          *(const uint4v*)(wbf1r + (size_t)co * 512 + k8 * 64 + 0 + quad * 8));
      short8 bf1 = __builtin_bit_cast(short8,
          *(const uint4v*)(wbf1r + (size_t)co * 512 + k8 * 64 + 32 + quad * 8));
      acc[nt] = __builtin_amdgcn_mfma_f32_16x16x32_bf16(af0, bf0, acc[nt], 0, 0, 0);
      acc[nt] = __builtin_amdgcn_mfma_f32_16x16x32_bf16(af1, bf1, acc[nt], 0, 0, 0);
    }
  }
  #pragma unroll
  for (int nt = 0; nt < 4; ++nt) {
    int c = nt * 16 + nl;
    float scc = sc[c], sbc = sb[c];
    #pragma unroll
    for (int r = 0; r < 4; ++r) {
      int t = t0 + w * 16 + quad * 4 + r;
      if (t < TT)
        x2bf[((size_t)b * TT + t) * CC + c] = bfr(fmaxf(acc[nt][r] * scc + sbc, 0.0f));
    }
  }
}

// ---------------- K3: bi-LSTM via MFMA, chunked I/O (unchanged, R10 structure) ----------------
__global__ __launch_bounds__(256) void k_lstm_m(const unsigned short* __restrict__ x2bf,
    const unsigned short* __restrict__ wihbf, const unsigned short* __restrict__ whhbf,
    const float* __restrict__ lbias,
    unsigned short* __restrict__ values, float* __restrict__ hT)
{
  int b0 = blockIdx.x * 16;
  int dir = blockIdx.y;
  int tid = threadIdx.x;
  int w = tid >> 6, lane = tid & 63, l15 = lane & 15, quad = lane >> 4;
  int h0 = w * 16;
  const unsigned short* wih = wihbf + dir * 16384;
  const unsigned short* whh = whhbf + dir * 16384;

  short8 bx[4][2], bh[4][2];
  float bias_v[4];
  #pragma unroll
  for (int g = 0; g < 4; ++g) {
    int row = g * 64 + h0 + l15;
    #pragma unroll
    for (int k = 0; k < 2; ++k) {
      bx[g][k] = __builtin_bit_cast(short8, *(const uint4v*)(wih + row * 64 + k * 32 + quad * 8));
      bh[g][k] = __builtin_bit_cast(short8, *(const uint4v*)(whh + row * 64 + k * 32 + quad * 8));
    }
    bias_v[g] = lbias[dir * 256 + g * 64 + h0 + l15];
  }

  __shared__ __align__(16) unsigned short xls[2][8][16 * 72];
  __shared__ __align__(16) unsigned short hist[8][16 * 72];
  for (int j = tid; j < 16 * 72; j += 256) hist[7][j] = 0;  // h_{-1} = 0

  int bl = tid >> 4, d4 = tid & 15;
  const unsigned short* xrow = x2bf + ((size_t)(b0 + bl) * TT) * 64 + d4 * 4;

  uint2 xr[8];
  #pragma unroll
  for (int k = 0; k < 8; ++k) {               // chunk 0
    int t = dir ? (TT - 1 - k) : k;
    xr[k] = *(const uint2*)(xrow + (size_t)t * 64);
  }
  #pragma unroll
  for (int k = 0; k < 8; ++k)
    *(uint2*)(&xls[0][k][bl * 72 + d4 * 4]) = xr[k];
  #pragma unroll
  for (int k = 0; k < 8; ++k) {               // chunk 1
    int s = 8 + k;
    int t = dir ? (TT - 1 - s) : s;
    xr[k] = *(const uint2*)(xrow + (size_t)t * 64);
  }
  __syncthreads();

  float cst[4] = {0.f, 0.f, 0.f, 0.f};
  for (int c = 0; c < 31; ++c) {
    int buf = c & 1;
    #pragma unroll
    for (int sl = 0; sl < 8; ++sl) {
      int hp = (sl + 7) & 7;
      short8 ax0 = __builtin_bit_cast(short8, *(const uint4v*)(&xls[buf][sl][l15 * 72 + quad * 8]));
      short8 ax1 = __builtin_bit_cast(short8, *(const uint4v*)(&xls[buf][sl][l15 * 72 + 32 + quad * 8]));
      short8 ah0 = __builtin_bit_cast(short8, *(const uint4v*)(&hist[hp][l15 * 72 + quad * 8]));
      short8 ah1 = __builtin_bit_cast(short8, *(const uint4v*)(&hist[hp][l15 * 72 + 32 + quad * 8]));
      f32x4 aX[4], aH[4];
      #pragma unroll
      for (int g = 0; g < 4; ++g) {
        aX[g] = (f32x4){bias_v[g], bias_v[g], bias_v[g], bias_v[g]};
        aX[g] = __builtin_amdgcn_mfma_f32_16x16x32_bf16(ax0, bx[g][0], aX[g], 0, 0, 0);
        aX[g] = __builtin_amdgcn_mfma_f32_16x16x32_bf16(ax1, bx[g][1], aX[g], 0, 0, 0);
        aH[g] = (f32x4){0.f, 0.f, 0.f, 0.f};
        aH[g] = __builtin_amdgcn_mfma_f32_16x16x32_bf16(ah0, bh[g][0], aH[g], 0, 0, 0);
        aH[g] = __builtin_amdgcn_mfma_f32_16x16x32_bf16(ah1, bh[g][1], aH[g], 0, 0, 0);
      }
      #pragma unroll
      for (int r = 0; r < 4; ++r) {
        float ig = sigf(aX[0][r] + aH[0][r]);
        float fg = sigf(aX[1][r] + aH[1][r]);
        float gg = tanhff(aX[2][r] + aH[2][r]);
        float og = sigf(aX[3][r] + aH[3][r]);
        cst[r] = fg * cst[r] + ig * gg;
        float hh = og * tanhff(cst[r]);
        hist[sl][(quad * 4 + r) * 72 + h0 + l15] = bfr(hh);
        if (c == 30 && sl == 6) {             // global step 246 = last real step
          int bglob = b0 + quad * 4 + r;
          hT[((size_t)dir * BB + bglob) * 64 + h0 + l15] = hh;
        }
      }
      lds_barrier();
    }
    uint4v dv[4];
    #pragma unroll
    for (int i = 0; i < 4; ++i) {
      int flat = i * 256 + tid;
      int sl = flat >> 7, wb = (flat >> 3) & 15, c8 = flat & 7;
      dv[i] = *(const uint4v*)(&hist[sl][wb * 72 + c8 * 8]);
    }
    #pragma unroll
    for (int i = 0; i < 4; ++i) {
      int flat = i * 256 + tid;
      int sl = flat >> 7, wb = (flat >> 3) & 15, c8 = flat & 7;
      int s = c * 8 + sl;
      if (s < TT) {
        int t = dir ? (TT - 1 - s) : s;
        *(uint4v*)(values + ((size_t)(b0 + wb) * TT + t) * D2 + dir * 64 + c8 * 8) = dv[i];
      }
    }
    if (c < 30) {
      #pragma unroll
      for (int k = 0; k < 8; ++k)
        *(uint2*)(&xls[1 - buf][k][bl * 72 + d4 * 4]) = xr[k];
      #pragma unroll
      for (int k = 0; k < 8; ++k) {
        int s2 = (c + 2) * 8 + k;
        if (s2 > TT - 1) s2 = TT - 1;
        int t2 = dir ? (TT - 1 - s2) : s2;
        xr[k] = *(const uint2*)(xrow + (size_t)t2 * 64);
      }
    }
    lds_barrier();
  }
}

// ---------------- K3b: q2 = h_n @ W2^T + W2_b ----------------
__global__ __launch_bounds__(128) void k_q2(const float* __restrict__ hT,
    const float* __restrict__ W2, const float* __restrict__ W2b,
    float* __restrict__ q2)
{
  int b = blockIdx.x;
  int tid = threadIdx.x;
  __shared__ float4 hn4[32];
  ((float*)hn4)[tid] = hT[(size_t)b * 128 + tid];
  __syncthreads();
  const float4* w4 = (const float4*)(W2 + (size_t)tid * 128);
  float a = W2b[tid];
  #pragma unroll
  for (int j = 0; j < 32; ++j) {
    float4 w = w4[j]; float4 h = hn4[j];
    a += w.x * h.x + w.y * h.y + w.z * h.z + w.w * h.w;
  }
  q2[(size_t)b * 128 + tid] = a;
}

// ---------------- K4: score via MFMA -> scoreT[b][n][t] bf16 ----------------
__global__ __launch_bounds__(256) void k_score_m(const unsigned short* __restrict__ vbf,
    const unsigned short* __restrict__ W1bf, const float* __restrict__ W1b,
    const float* __restrict__ q2, const unsigned short* __restrict__ Vbf,
    const float* __restrict__ Vb, unsigned short* __restrict__ scoreT)
{
  int b = blockIdx.x, t0 = blockIdx.y * 64;
  int tid = threadIdx.x, w = tid >> 6, lane = tid & 63, l15 = lane & 15, quad = lane >> 4;
  __shared__ unsigned short us[64 * 136];
  __shared__ unsigned short sc2[64 * 213];
  const unsigned short* arow = vbf + ((size_t)b * TT + t0 + w * 16 + l15) * 128;
  short8 ax[4];
  #pragma unroll
  for (int ks = 0; ks < 4; ++ks)
    ax[ks] = __builtin_bit_cast(short8, *(const uint4v*)(arow + ks * 32 + quad * 8));
  #pragma unroll
  for (int nt = 0; nt < 8; ++nt) {
    int n = nt * 16 + l15;
    float base = W1b[n] + q2[(size_t)b * 128 + n];
    f32x4 acc = (f32x4){base, base, base, base};
    #pragma unroll
    for (int ks = 0; ks < 4; ++ks) {
      short8 bf = __builtin_bit_cast(short8,
          *(const uint4v*)(W1bf + (size_t)n * 128 + ks * 32 + quad * 8));
      acc = __builtin_amdgcn_mfma_f32_16x16x32_bf16(ax[ks], bf, acc, 0, 0, 0);
    }
    #pragma unroll
    for (int r = 0; r < 4; ++r)
      us[(w * 16 + quad * 4 + r) * 136 + nt * 16 + l15] = bfr(tanhff(acc[r]));
  }
  __syncthreads();
  short8 au[4];
  #pragma unroll
  for (int ks = 0; ks < 4; ++ks)
    au[ks] = __builtin_bit_cast(short8, *(const uint4v*)(&us[(w * 16 + l15) * 136 + ks * 32 + quad * 8]));
  for (int nt2 = 0; nt2 < 13; ++nt2) {
    int n = nt2 * 16 + l15;
    float b2 = (n < NTF) ? Vb[n] : 0.0f;
    f32x4 a2 = (f32x4){b2, b2, b2, b2};
    #pragma unroll
    for (int ks = 0; ks < 4; ++ks) {
      short8 bf = __builtin_bit_cast(short8,
          *(const uint4v*)(Vbf + (size_t)n * 128 + ks * 32 + quad * 8));
      a2 = __builtin_amdgcn_mfma_f32_16x16x32_bf16(au[ks], bf, a2, 0, 0, 0);
    }
    #pragma unroll
    for (int r = 0; r < 4; ++r) {
      int tl = w * 16 + quad * 4 + r;
      sc2[tl * 213 + n] = bfr(a2[r]);
    }
  }
  __syncthreads();
  int tg = tid & 3;
  #pragma unroll
  for (int pp = 0; pp < 4; ++pp) {
    int nrow = pp * 64 + (tid >> 2);
    if (nrow < NTF) {
      unsigned uu[8];
      #pragma unroll
      for (int k2 = 0; k2 < 8; ++k2) {
        unsigned lo = sc2[(tg * 16 + k2 * 2) * 213 + nrow];
        unsigned hi = sc2[(tg * 16 + k2 * 2 + 1) * 213 + nrow];
        uu[k2] = lo | (hi << 16);
      }
      size_t dst = ((size_t)b * 208 + nrow) * 256 + t0 + tg * 16;
      *(uint4v*)(scoreT + dst) = (uint4v){uu[0], uu[1], uu[2], uu[3]};
      *(uint4v*)(scoreT + dst + 8) = (uint4v){uu[4], uu[5], uu[6], uu[7]};
    }
  }
}

// ---------------- K5: softmax over t, row-wise on scoreT ----------------
__global__ __launch_bounds__(256) void k_softmax(unsigned short* __restrict__ scoreT,
    float* __restrict__ sinv)
{
  int b = blockIdx.x, nc = blockIdx.y;
  int tid = threadIdx.x;
  int n = nc * 64 + (tid >> 2), tg = tid & 3;
  if (n >= NTF) return;
  unsigned short* row = scoreT + ((size_t)b * 208 + n) * 256 + tg * 64;
  uint4v ld[8];
  #pragma unroll
  for (int i = 0; i < 8; ++i) ld[i] = *(const uint4v*)(row + i * 8);
  float m = -1e30f;
  #pragma unroll
  for (int i = 0; i < 8; ++i) {
    #pragma unroll
    for (int u = 0; u < 4; ++u) {
      unsigned xv = ld[i][u];
      int t0 = tg * 64 + i * 8 + u * 2;
      float a = __builtin_bit_cast(float, xv << 16);
      float c = __builtin_bit_cast(float, xv & 0xffff0000u);
      if (t0 < TT) m = fmaxf(m, a);
      if (t0 + 1 < TT) m = fmaxf(m, c);
    }
  }
  m = fmaxf(m, __shfl_xor(m, 1, 64));
  m = fmaxf(m, __shfl_xor(m, 2, 64));
  float s = 0.0f;
  #pragma unroll
  for (int i = 0; i < 8; ++i) {
    uint4v ov;
    #pragma unroll
    for (int u = 0; u < 4; ++u) {
      unsigned xv = ld[i][u];
      int t0 = tg * 64 + i * 8 + u * 2;
      float a = __builtin_bit_cast(float, xv << 16);
      float c = __builtin_bit_cast(float, xv & 0xffff0000u);
      float ea = (t0 < TT) ? __expf(a - m) : 0.0f;
      float ec = (t0 + 1 < TT) ? __expf(c - m) : 0.0f;
      s += ea + ec;
      ov[u] = (unsigned)bfr(ea) | ((unsigned)bfr(ec) << 16);
    }
    *(uint4v*)(row + i * 8) = ov;
  }
  s += __shfl_xor(s, 1, 64);
  s += __shfl_xor(s, 2, 64);
  if (tg == 0) sinv[(size_t)b * NTF + n] = __builtin_amdgcn_rcpf(s);
}

// ---------------- K6: context via MFMA -> ctxbf (bf16) ----------------
__global__ __launch_bounds__(256) void k_ctx_m(const unsigned short* __restrict__ vbf,
    const unsigned short* __restrict__ scoreT, const float* __restrict__ sinv,
    unsigned short* __restrict__ ctxbf)
{
  int b = blockIdx.x;
  int tid = threadIdx.x, w = tid >> 6, lane = tid & 63, l15 = lane & 15, quad = lane >> 4;
  __shared__ __align__(16) unsigned short vt[128 * 264];  // [d][t]
  __shared__ float sls[208];
  for (int flat = tid; flat < 247 * 64; flat += 256) {
    int t = flat >> 6, dp = flat & 63;
    unsigned v = *(const unsigned*)(vbf + ((size_t)b * TT + t) * D2 + dp * 2);
    vt[(dp * 2) * 264 + t] = (unsigned short)(v & 0xffffu);
    vt[(dp * 2 + 1) * 264 + t] = (unsigned short)(v >> 16);
  }
  for (int j = tid; j < 128 * 9; j += 256) {
    int d = j / 9, t = 247 + (j % 9);
    vt[d * 264 + t] = 0;
  }
  for (int j = tid; j < 208; j += 256) sls[j] = (j < NTF) ? sinv[(size_t)b * NTF + j] : 0.0f;
  __syncthreads();

  const unsigned short* abase = scoreT + (size_t)b * 208 * 256;
  for (int mi = 0; mi < 4; ++mi) {
    int mt = w + 4 * mi;
    if (mt >= 13) continue;
    const unsigned short* arow = abase + (size_t)(mt * 16 + l15) * 256;
    short8 af[8];
    #pragma unroll
    for (int ks = 0; ks < 8; ++ks)
      af[ks] = __builtin_bit_cast(short8, *(const uint4v*)(arow + ks * 32 + quad * 8));
    f32x4 acc[8];
    #pragma unroll
    for (int dt = 0; dt < 8; ++dt) {
      acc[dt] = (f32x4){0.f, 0.f, 0.f, 0.f};
      #pragma unroll
      for (int ks = 0; ks < 8; ++ks) {
        short8 bf = __builtin_bit_cast(short8,
            *(const uint4v*)(&vt[(dt * 16 + l15) * 264 + ks * 32 + quad * 8]));
        acc[dt] = __builtin_amdgcn_mfma_f32_16x16x32_bf16(af[ks], bf, acc[dt], 0, 0, 0);
      }
    }
    #pragma unroll
    for (int r = 0; r < 4; ++r) {
      int n = mt * 16 + quad * 4 + r;
      if (n < NTF) {
        float rs = sls[n];
        #pragma unroll
        for (int dt = 0; dt < 8; ++dt)
          ctxbf[((size_t)b * NTF + n) * D2 + dt * 16 + l15] = bfr(acc[dt][r] * rs);
      }
    }
  }
}

// ---------------- K7: per-TF heads via MFMA ----------------
// GEMM per n: M=128 batch tile, N=64 (o), K=128; A,B frags direct from global bf16.
__global__ __launch_bounds__(256) void k_heads_m(const unsigned short* __restrict__ ctxbf,
    const unsigned short* __restrict__ f1bf, const float* __restrict__ fc1b,
    const float* __restrict__ fc2w, const float* __restrict__ fc2b,
    float* __restrict__ out)
{
  int n = blockIdx.x;
  int b0 = blockIdx.y * 128;
  int tid = threadIdx.x, w = tid >> 6, lane = tid & 63, l15 = lane & 15, quad = lane >> 4;
  // B-frags: fc1 rows for o = nt*16+l15 (resident)
  short8 bfr_[4][4];
  float f1bv[4], f2v[4];
  #pragma unroll
  for (int nt = 0; nt < 4; ++nt) {
    int o = nt * 16 + l15;
    #pragma unroll
    for (int ks = 0; ks < 4; ++ks)
      bfr_[nt][ks] = __builtin_bit_cast(short8,
          *(const uint4v*)(f1bf + ((size_t)n * 64 + o) * 128 + ks * 32 + quad * 8));
    f1bv[nt] = fc1b[n * 64 + o];
    f2v[nt] = fc2w[n * 64 + o];
  }
  float f2b = fc2b[n];
  #pragma unroll
  for (int mi = 0; mi < 2; ++mi) {
    int m16 = (w * 2 + mi) * 16;
    const unsigned short* arow = ctxbf + ((size_t)(b0 + m16 + l15) * NTF + n) * 128;
    short8 af[4];
    #pragma unroll
    for (int ks = 0; ks < 4; ++ks)
      af[ks] = __builtin_bit_cast(short8, *(const uint4v*)(arow + ks * 32 + quad * 8));
    f32x4 acc[4];
    #pragma unroll
    for (int nt = 0; nt < 4; ++nt) {
      acc[nt] = (f32x4){0.f, 0.f, 0.f, 0.f};
      #pragma unroll
      for (int ks = 0; ks < 4; ++ks)
        acc[nt] = __builtin_amdgcn_mfma_f32_16x16x32_bf16(af[ks], bfr_[nt][ks], acc[nt], 0, 0, 0);
    }
    #pragma unroll
    for (int r = 0; r < 4; ++r) {
      float part = 0.0f;
      #pragma unroll
      for (int nt = 0; nt < 4; ++nt)
        part += fmaxf(acc[nt][r] + f1bv[nt], 0.0f) * f2v[nt];
      part += __shfl_xor(part, 1, 64);
      part += __shfl_xor(part, 2, 64);
      part += __shfl_xor(part, 4, 64);
      part += __shfl_xor(part, 8, 64);
      if (l15 == 0) {
        int bb = b0 + m16 + quad * 4 + r;
        out[(size_t)bb * NTF + n] = part + f2b;
      }
    }
  }
}

extern "C" void kernel_launch(void* const* d_in, const int* in_sizes, int n_in,
                              void* d_out, int out_size, void* d_ws, size_t ws_size,
                              hipStream_t stream)
{
  const float* x    = (const float*)d_in[0];
  const float* c0w  = (const float*)d_in[1];
  const float* c0b  = (const float*)d_in[2];
  const float* g0   = (const float*)d_in[3];
  const float* be0  = (const float*)d_in[4];
  const float* m0   = (const float*)d_in[5];
  const float* v0   = (const float*)d_in[6];
  const float* c1w  = (const float*)d_in[7];
  const float* c1b  = (const float*)d_in[8];
  const float* g1   = (const float*)d_in[9];
  const float* be1  = (const float*)d_in[10];
  const float* m1   = (const float*)d_in[11];
  const float* v1   = (const float*)d_in[12];
  const float* wihf = (const float*)d_in[13];
  const float* whhf = (const float*)d_in[14];
  const float* bihf = (const float*)d_in[15];
  const float* bhhf = (const float*)d_in[16];
  const float* wihb = (const float*)d_in[17];
  const float* whhb = (const float*)d_in[18];
  const float* bihb = (const float*)d_in[19];
  const float* bhhb = (const float*)d_in[20];
  const float* W1w  = (const float*)d_in[21];
  const float* W1b  = (const float*)d_in[22];
  const float* W2w  = (const float*)d_in[23];
  const float* W2b  = (const float*)d_in[24];
  const float* Vw   = (const float*)d_in[25];
  const float* Vb   = (const float*)d_in[26];
  const float* f1w  = (const float*)d_in[27];
  const float* f1b  = (const float*)d_in[28];
  const float* f2w  = (const float*)d_in[29];
  const float* f2b  = (const float*)d_in[30];

  float* ws = (float*)d_ws;
  unsigned short* scoreT = (unsigned short*)ws;            // [b][208][256] bf16
  unsigned short* pbf  = (unsigned short*)ws;              // overlaps scoreT region (dead first)
  unsigned short* x2bf = (unsigned short*)(ws + 8323072);
  unsigned short* vbf  = (unsigned short*)(ws + 25292800);
  float* hT     = ws + 33387520;
  float* q2     = ws + 33453056;
  float* sinv   = ws + 33518592;
  unsigned short* ctxbf = (unsigned short*)(ws + 33620992); // 13.1M shorts
  unsigned short* wbf0  = (unsigned short*)(ws + 46728192);
  unsigned short* wbf1r = (unsigned short*)(ws + 46729216);
  unsigned short* wihbf = (unsigned short*)(ws + 46745600);
  unsigned short* whhbf = (unsigned short*)(ws + 46761984);
  float* lbias          = ws + 46778368;
  unsigned short* W1bf  = (unsigned short*)(ws + 46778880);
  unsigned short* Vbf   = (unsigned short*)(ws + 46787072);
  unsigned short* f1bf  = (unsigned short*)(ws + 46800384); // 1,638,400 shorts
  float* out    = (float*)d_out;

  k_cvt<<<dim3(6400), 256, 0, stream>>>(c0w, c1w, wihf, whhf, wihb, whhb,
                                        bihf, bhhf, bihb, bhhb, W1w, Vw, f1w,
                                        wbf0, wbf1r, wihbf, whhbf, lbias, W1bf, Vbf, f1bf);
  k_conv0m<<<dim3(BB, 16), 256, 0, stream>>>(x, wbf0, c0b, g0, be0, m0, v0, pbf);
  k_conv1m<<<dim3(BB, 4), 256, 0, stream>>>(pbf, wbf1r, c1b, g1, be1, m1, v1, x2bf);
  k_lstm_m<<<dim3(BB / 16, 2), 256, 0, stream>>>(x2bf, wihbf, whhbf, lbias, vbf, hT);
  k_q2<<<dim3(BB), 128, 0, stream>>>(hT, W2w, W2b, q2);
  k_score_m<<<dim3(BB, 4), 256, 0, stream>>>(vbf, W1bf, W1b, q2, Vbf, Vb, scoreT);
  k_softmax<<<dim3(BB, 4), 256, 0, stream>>>(scoreT, sinv);
  k_ctx_m<<<dim3(BB), 256, 0, stream>>>(vbf, scoreT, sinv, ctxbf);
  k_heads_m<<<dim3(NTF, 4), 256, 0, stream>>>(ctxbf, f1bf, f1b, f2w, f2b, out);
}